// Round 15
// baseline (216.574 us; speedup 1.0000x reference)
//
#include <hip/hip_runtime.h>
#include <hip/hip_bf16.h>
#include <math.h>

// ---- problem constants ----
// bs=32, S=512, D=256, HS=4 heads (head dim = D = 256!), NT = 16384 tokens
// patch: NP=16 patches x P=16, CC=128, HP=4 heads x CE=32

typedef __attribute__((ext_vector_type(8))) short bf16x8;
typedef __attribute__((ext_vector_type(4))) float f32x4;

__device__ __forceinline__ unsigned short f2bf(float f){
  unsigned u = __float_as_uint(f);
  return (unsigned short)((u + 0x7FFFu + ((u >> 16) & 1u)) >> 16);   // RNE
}
__device__ __forceinline__ unsigned pack2bf(float a, float b){
  return (unsigned)f2bf(a) | ((unsigned)f2bf(b) << 16);
}
__device__ __forceinline__ bf16x8 pack8(float a0,float a1,float a2,float a3,
                                        float a4,float a5,float a6,float a7){
  union { bf16x8 v; unsigned u[4]; } t;
  t.u[0]=pack2bf(a0,a1); t.u[1]=pack2bf(a2,a3);
  t.u[2]=pack2bf(a4,a5); t.u[3]=pack2bf(a6,a7);
  return t.v;
}
// async 16B global->LDS (dest = wave-uniform base + lane*16; SOURCE per-lane)
__device__ __forceinline__ void gld16(const void* g, void* l){
  __builtin_amdgcn_global_load_lds((const __attribute__((address_space(1))) void*)g,
                                   (__attribute__((address_space(3))) void*)l, 16, 0, 0);
}

// ---------------------------------------------------------------------------
// cvt: f32 -> bf16, vectorized x4
// ---------------------------------------------------------------------------
__global__ __launch_bounds__(256) void k_cvt(const float* __restrict__ src,
                                             unsigned short* __restrict__ dst, int n4)
{
  int i = blockIdx.x * 256 + threadIdx.x;
  if (i < n4){
    float4 v = ((const float4*)src)[i];
    ushort4 o;
    o.x = f2bf(v.x); o.y = f2bf(v.y); o.z = f2bf(v.z); o.w = f2bf(v.w);
    ((ushort4*)dst)[i] = o;
  }
}

// ---------------------------------------------------------------------------
// k_packw: pre-pack patch weights into per-lane MFMA B-fragment layout.
// ---------------------------------------------------------------------------
__global__ __launch_bounds__(256) void k_packw(
    const float* __restrict__ Wqc, const float* __restrict__ Wkc,
    const float* __restrict__ Wvl, const float* __restrict__ Wlo,
    unsigned short* __restrict__ Wp)
{
  int it = blockIdx.x * 256 + threadIdx.x;     // 28*64 = 1792 items
  if (it >= 1792) return;
  int ch = it >> 6, lane = it & 63;
  int g = lane >> 4, li = lane & 15;
  unsigned short o[8];
  if (ch < 24){
    int m = ch >> 3, nc = ch & 7;
    const float* W = (m == 0) ? Wqc : (m == 1 ? Wkc : Wvl);
    int c = nc * 16 + li;
    #pragma unroll
    for (int j = 0; j < 8; ++j){
      int k = g * 8 + j;
      o[j] = (k < 16) ? f2bf(W[c * 16 + k]) : (unsigned short)0;
    }
  } else {
    int kc = ch - 24;
    #pragma unroll
    for (int j = 0; j < 8; ++j){
      int k = kc * 32 + g * 8 + j;
      o[j] = f2bf(Wlo[li * 128 + k]);
    }
  }
  #pragma unroll
  for (int j = 0; j < 8; ++j) Wp[it * 8 + j] = o[j];
}

// ---------------------------------------------------------------------------
// k_gemm<0>: QKV projection, 128x128 tile, XCD-chunked swizzle.
// Q/K scatter [bh][s][d] bf16; V -> tiled VtT (attn LDS image).
// ---------------------------------------------------------------------------
template<int EPI>
__global__ __launch_bounds__(256) void k_gemm(
    const unsigned short* __restrict__ A,   // [M,K] bf16
    const unsigned short* __restrict__ W,   // [N,K] bf16
    const float* __restrict__ b0,
    const float* __restrict__ b1,
    const float* __restrict__ b2,
    void* __restrict__ outp,
    unsigned short* __restrict__ Kw_,
    unsigned short* __restrict__ Vt_,
    int K)
{
  extern __shared__ char sm[];
  const int tid = threadIdx.x;
  const int wid = tid >> 6, lane = tid & 63;
  const int g = lane >> 4, li = lane & 15;
  const int wm = wid >> 1, wn = wid & 1;
  const int lin = blockIdx.x + (blockIdx.y << 7);
  const int nl2 = ((lin & 7) * 384) + (lin >> 3);
  const int mt  = nl2 / 24;
  const int nt  = nl2 - mt * 24;
  const int m0 = mt << 7, n0 = nt << 7;

  const unsigned short* Ab = A + (size_t)m0 * K;
  const unsigned short* Wb = W + (size_t)n0 * K;

  auto stage = [&](char* dst, const unsigned short* src, int k0){
    #pragma unroll
    for (int r = 0; r < 4; ++r){
      int row = (r << 5) + (tid >> 3);
      int cb  = (tid & 7) << 4;
      int cbs = cb ^ ((row & 7) << 4);
      gld16(src + row * K + k0 + (cbs >> 1), dst + (r << 12) + (wid << 10));
    }
  };

  f32x4 acc[4][4];
  #pragma unroll
  for (int mf = 0; mf < 4; ++mf)
    #pragma unroll
    for (int nf = 0; nf < 4; ++nf) acc[mf][nf] = (f32x4){0.f,0.f,0.f,0.f};

  const int nk = K >> 6;
  stage(sm, Ab, 0); stage(sm + 32768, Wb, 0);
  for (int kt = 0; kt < nk; ++kt){
    char* Acur = (kt & 1) ? (sm + 16384) : sm;
    char* Wcur = (kt & 1) ? (sm + 49152) : (sm + 32768);
    if (kt + 1 < nk){
      char* Anxt = (kt & 1) ? sm : (sm + 16384);
      char* Wnxt = (kt & 1) ? (sm + 32768) : (sm + 49152);
      stage(Anxt, Ab, (kt + 1) << 6);
      stage(Wnxt, Wb, (kt + 1) << 6);
    }
    __syncthreads();
    bf16x8 af[2][4], wf[2][4];
    #pragma unroll
    for (int kk = 0; kk < 2; ++kk){
      #pragma unroll
      for (int mf = 0; mf < 4; ++mf){
        int row  = (wm << 6) + (mf << 4) + li;
        int colb = ((kk << 6) + (g << 4)) ^ ((row & 7) << 4);
        af[kk][mf] = *(const bf16x8*)(Acur + (row << 7) + colb);
      }
      #pragma unroll
      for (int nf = 0; nf < 4; ++nf){
        int row  = (wn << 6) + (nf << 4) + li;
        int colb = ((kk << 6) + (g << 4)) ^ ((row & 7) << 4);
        wf[kk][nf] = *(const bf16x8*)(Wcur + (row << 7) + colb);
      }
    }
    #pragma unroll
    for (int kk = 0; kk < 2; ++kk)
      #pragma unroll
      for (int mf = 0; mf < 4; ++mf)
        #pragma unroll
        for (int nf = 0; nf < 4; ++nf)
          acc[mf][nf] = __builtin_amdgcn_mfma_f32_16x16x32_bf16(af[kk][mf], wf[kk][nf], acc[mf][nf], 0, 0, 0);
    __syncthreads();
  }

  const int chunk = n0 >> 10;
  const float* bias = (chunk == 0) ? b0 : (chunk == 1 ? b1 : b2);
  const int nq0 = n0 & 1023;
  const int h = nq0 >> 8;                 // uniform per block
  if (chunk == 2){
    const int b  = m0 >> 9;
    const int bh = (b << 2) + h;
    const int d0g = (nq0 & 255) + (wn << 6);
    const int s0g = (m0 & 511) + (wm << 6);
    char* const TB = sm + (wid << 13);     // 8KB per wave
    #pragma unroll
    for (int nf = 0; nf < 4; ++nf){
      const int dloc = (nf << 4) + li;
      const float bv = bias[nq0 + (wn << 6) + (nf << 4) + li];
      #pragma unroll
      for (int mf = 0; mf < 4; ++mf){
        ushort4 pk;
        pk.x = f2bf(acc[mf][nf][0] + bv); pk.y = f2bf(acc[mf][nf][1] + bv);
        pk.z = f2bf(acc[mf][nf][2] + bv); pk.w = f2bf(acc[mf][nf][3] + bv);
        const int unit = ((mf << 2) + g) ^ (dloc & 7);
        *(ushort4*)(TB + (dloc << 7) + (unit << 3)) = pk;
      }
    }
    __asm__ volatile("s_waitcnt lgkmcnt(0)" ::: "memory");
    __builtin_amdgcn_sched_barrier(0);
    #pragma unroll
    for (int p = 0; p < 8; ++p){
      const int dl = (p << 3) + (lane >> 3);
      const int u0 = (lane & 7) << 1;
      uint2 ua = *(const uint2*)(TB + (dl << 7) + (((u0)     ^ (dl & 7)) << 3));
      uint2 ub = *(const uint2*)(TB + (dl << 7) + (((u0 + 1) ^ (dl & 7)) << 3));
      uint4 vv; vv.x = ua.x; vv.y = ua.y; vv.z = ub.x; vv.w = ub.y;
      const int dglob = d0g + dl;
      const int sglb  = s0g + ((lane & 7) << 3);     // 8-aligned
      const int tt    = sglb >> 5;
      const int sc    = (sglb & 31) >> 3;            // s-chunk 0..3
      const int row   = dglob >> 1;
      char* vdst = (char*)Vt_ + ((size_t)bh << 18) + (tt << 14) + (row << 7)
                 + ((dglob & 1) << 6) + ((sc ^ (row & 3)) << 4);
      *(uint4*)vdst = vv;
    }
  } else {
    unsigned short* dst = (chunk == 0) ? (unsigned short*)outp : Kw_;
    #pragma unroll
    for (int nf = 0; nf < 4; ++nf){
      const int nq = nq0 + (wn << 6) + (nf << 4) + li;
      const int d = nq & 255;
      const float bv = bias[nq];
      #pragma unroll
      for (int mf = 0; mf < 4; ++mf){
        const int mbase = m0 + (wm << 6) + (mf << 4) + (g << 2);
        #pragma unroll
        for (int r = 0; r < 4; ++r){
          const int m = mbase + r;
          const int b = m >> 9, s = m & 511;
          dst[(size_t)((((b << 2) + h) << 9) + s) * 256 + d] = f2bf(acc[mf][nf][r] + bv);
        }
      }
    }
  }
}

// ---------------------------------------------------------------------------
// k_gemm_ln: out = LN(A @ W^T + bias + resid). 64x256 tile, BK=32, 4 waves.
// ---------------------------------------------------------------------------
__global__ __launch_bounds__(256) void k_gemm_ln(
    const unsigned short* __restrict__ A,   // [M,K] bf16
    const unsigned short* __restrict__ W,   // [256,K] bf16
    const float* __restrict__ bias,
    const float* __restrict__ resid,        // f32 [M,256]
    float* __restrict__ outp,               // f32 [M,256]
    int K)
{
  extern __shared__ char sm[];
  const int tid = threadIdx.x;
  const int wid = tid >> 6, lane = tid & 63;
  const int g = lane >> 4, li = lane & 15;
  const int m0 = blockIdx.x << 6;
  const unsigned short* Ab = A + (size_t)m0 * K;

  auto stageA = [&](char* dst, int k0){
    int row = tid >> 2;
    int cs  = (tid & 3) ^ (row & 3);
    gld16(Ab + (size_t)row * K + k0 + (cs << 3), dst + (wid << 10));
  };
  auto stageW = [&](char* dst, int k0){
    #pragma unroll
    for (int cc = 0; cc < 4; ++cc){
      int u = (cc << 8) + tid;
      int row = u >> 2;
      int cs  = (u & 3) ^ (row & 3);
      gld16(W + (size_t)row * K + k0 + (cs << 3), dst + (cc << 12) + (wid << 10));
    }
  };

  f32x4 acc[4][4];
  #pragma unroll
  for (int mf = 0; mf < 4; ++mf)
    #pragma unroll
    for (int nf = 0; nf < 4; ++nf) acc[mf][nf] = (f32x4){0.f,0.f,0.f,0.f};

  const int nk = K >> 5;
  stageA(sm, 0); stageW(sm + 8192, 0);
  for (int kt = 0; kt < nk; ++kt){
    char* Acur = (kt & 1) ? (sm + 4096)  : sm;
    char* Wcur = (kt & 1) ? (sm + 24576) : (sm + 8192);
    if (kt + 1 < nk){
      stageA((kt & 1) ? sm : (sm + 4096), (kt + 1) << 5);
      stageW((kt & 1) ? (sm + 8192) : (sm + 24576), (kt + 1) << 5);
    }
    __syncthreads();
    bf16x8 af[4], wf[4];
    #pragma unroll
    for (int mf = 0; mf < 4; ++mf){
      int row  = (mf << 4) + li;
      int colb = (g << 4) ^ ((row & 3) << 4);
      af[mf] = *(const bf16x8*)(Acur + (row << 6) + colb);
    }
    #pragma unroll
    for (int nf = 0; nf < 4; ++nf){
      int row  = (wid << 6) + (nf << 4) + li;
      int colb = (g << 4) ^ ((row & 3) << 4);
      wf[nf] = *(const bf16x8*)(Wcur + (row << 6) + colb);
    }
    #pragma unroll
    for (int mf = 0; mf < 4; ++mf)
      #pragma unroll
      for (int nf = 0; nf < 4; ++nf)
        acc[mf][nf] = __builtin_amdgcn_mfma_f32_16x16x32_bf16(af[mf], wf[nf], acc[mf][nf], 0, 0, 0);
    __syncthreads();
  }

  float bv[4];
  #pragma unroll
  for (int nf = 0; nf < 4; ++nf) bv[nf] = bias[(wid << 6) + (nf << 4) + li];
  #pragma unroll
  for (int mf = 0; mf < 4; ++mf)
    #pragma unroll
    for (int r = 0; r < 4; ++r){
      const int m = (mf << 4) + (g << 2) + r;
      #pragma unroll
      for (int nf = 0; nf < 4; ++nf)
        acc[mf][nf][r] += bv[nf] + resid[(size_t)(m0 + m) * 256 + (wid << 6) + (nf << 4) + li];
    }

  float2* tbl = (float2*)sm;
  #pragma unroll
  for (int mf = 0; mf < 4; ++mf)
    #pragma unroll
    for (int r = 0; r < 4; ++r){
      float ps = 0.f, pq = 0.f;
      #pragma unroll
      for (int nf = 0; nf < 4; ++nf){
        float v = acc[mf][nf][r];
        ps += v; pq += v * v;
      }
      #pragma unroll
      for (int mk = 1; mk <= 8; mk <<= 1){
        ps += __shfl_xor(ps, mk); pq += __shfl_xor(pq, mk);
      }
      if (li == 0){
        float2 e; e.x = ps; e.y = pq;
        tbl[(wid << 6) + (mf << 4) + (g << 2) + r] = e;
      }
    }
  __syncthreads();
  #pragma unroll
  for (int mf = 0; mf < 4; ++mf)
    #pragma unroll
    for (int r = 0; r < 4; ++r){
      const int m = (mf << 4) + (g << 2) + r;
      float s = 0.f, q = 0.f;
      #pragma unroll
      for (int w = 0; w < 4; ++w){
        float2 e = tbl[(w << 6) + m];
        s += e.x; q += e.y;
      }
      float mean = s * (1.0f / 256.0f);
      float inv  = rsqrtf((q - 256.0f * mean * mean) * (1.0f / 255.0f));
      #pragma unroll
      for (int nf = 0; nf < 4; ++nf)
        outp[(size_t)(m0 + m) * 256 + (wid << 6) + (nf << 4) + li] =
            (acc[mf][nf][r] - mean) * inv;
    }
}

// ---------------------------------------------------------------------------
// K2: MFMA flash attention v9. 8 waves x 32 q = 256 q/block, grid (2,128).
// KVBLK=64 per barrier phase (2 x 32-t sub-iterations), dbuf 128KB LDS.
// Halves barrier count vs v8; registers/math identical.
// ---------------------------------------------------------------------------
__global__ __launch_bounds__(512, 1) void k_attn(const unsigned short* __restrict__ Qw,
                                                 const unsigned short* __restrict__ Kw,
                                                 const unsigned short* __restrict__ Vt,
                                                 unsigned short* __restrict__ Ow)
{
  extern __shared__ char smem[];
  const int tid  = threadIdx.x;
  const int wid  = tid >> 6, lane = tid & 63;
  const int g    = lane >> 4, li = lane & 15;
  const int dd   = blockIdx.x + (blockIdx.y << 1);
  const int nl   = ((dd & 7) << 5) + (dd >> 3);
  const int bh   = nl >> 1;
  const int sblk = (nl & 1) << 8;              // 256 q per block
  const int q0   = sblk + (wid << 5);          // 32 q per wave

  char* const KB0 = smem;            // 2 x 32KB
  char* const VB0 = smem + 65536;    // 2 x 32KB

  // K tile 64 rows x 512B = 32KB; wave owns 8 rows (4KB), 4 gld16/lane
  auto stageK = [&](char* kbuf, int t0){
    const unsigned short* base = Kw + ((size_t)(bh << 9) + t0 + (wid << 3)) * 256;
    char* dst = kbuf + (wid << 12);
    #pragma unroll
    for (int c = 0; c < 4; ++c){
      int r  = (c << 1) + (lane >> 5);                // 0..7 = tile_row & 7
      int cs = ((((lane & 31) << 4) ^ (r << 4)) >> 1);
      gld16(base + (r << 8) + cs, dst + (c << 10));
    }
  };
  // V: two 16KB tiles (2tt, 2tt+1) copied linearly; wave copies 4KB
  auto stageV = [&](char* vbuf, int tt){
    const char* src = (const char*)Vt + ((size_t)bh << 18) + ((size_t)tt << 15)
                    + (wid << 12) + (lane << 4);
    char* dst = vbuf + (wid << 12);
    #pragma unroll
    for (int c = 0; c < 4; ++c)
      gld16(src + (c << 10), dst + (c << 10));
  };

  bf16x8 qf[2][8];
  #pragma unroll
  for (int q2 = 0; q2 < 2; ++q2){
    const unsigned short* qp = Qw + ((size_t)(bh << 9) + q0 + (q2 << 4) + li) * 256 + (g << 3);
    #pragma unroll
    for (int kk = 0; kk < 8; ++kk)
      qf[q2][kk] = *(const bf16x8*)(qp + (kk << 5));
  }
  stageK(KB0, 0);
  stageV(VB0, 0);

  f32x4 o[16][2];
  #pragma unroll
  for (int df = 0; df < 16; ++df){
    o[df][0] = (f32x4){0.f,0.f,0.f,0.f};
    o[df][1] = (f32x4){0.f,0.f,0.f,0.f};
  }
  float m0 = -3.0e38f, m1 = -3.0e38f, l0 = 0.f, l1 = 0.f;

  const float inv256 = 1.0f / 256.0f;
  const int key   = (li & 7) << 4;
  const int laneA = ((g & 1) << 5) + li;
  const bool tf1  = (g >> 1);

  #pragma unroll 1
  for (int t = 0; t < 8; ++t){
    __syncthreads();
    char* kb64 = KB0 + ((t & 1) << 15);
    char* vb64 = VB0 + ((t & 1) << 15);
    if (t < 7){
      stageK(KB0 + (((t + 1) & 1) << 15), (t + 1) << 6);
      stageV(VB0 + (((t + 1) & 1) << 15), t + 1);
    }

    #pragma unroll
    for (int sub = 0; sub < 2; ++sub){
      char* kb = kb64 + (sub << 14);
      char* vb = vb64 + (sub << 14);

      f32x4 st[2][2];
      st[0][0] = (f32x4){0,0,0,0}; st[0][1] = (f32x4){0,0,0,0};
      st[1][0] = (f32x4){0,0,0,0}; st[1][1] = (f32x4){0,0,0,0};
      __builtin_amdgcn_s_setprio(1);
      #pragma unroll
      for (int kk = 0; kk < 8; ++kk){
        const int colb = ((kk << 6) + (g << 4)) ^ key;
        bf16x8 kf0 = *(const bf16x8*)(kb + (li << 9) + colb);
        bf16x8 kf1 = *(const bf16x8*)(kb + ((16 + li) << 9) + colb);
        st[0][0] = __builtin_amdgcn_mfma_f32_16x16x32_bf16(kf0, qf[0][kk], st[0][0], 0, 0, 0);
        st[0][1] = __builtin_amdgcn_mfma_f32_16x16x32_bf16(kf0, qf[1][kk], st[0][1], 0, 0, 0);
        st[1][0] = __builtin_amdgcn_mfma_f32_16x16x32_bf16(kf1, qf[0][kk], st[1][0], 0, 0, 0);
        st[1][1] = __builtin_amdgcn_mfma_f32_16x16x32_bf16(kf1, qf[1][kk], st[1][1], 0, 0, 0);
      }
      __builtin_amdgcn_s_setprio(0);

      float e0[8], e1[8];
      #pragma unroll
      for (int tf = 0; tf < 2; ++tf)
        #pragma unroll
        for (int r = 0; r < 4; ++r){
          e0[tf*4+r] = st[tf][0][r] * inv256;
          e1[tf*4+r] = st[tf][1][r] * inv256;
        }
      float p0 = e0[0], p1 = e1[0];
      #pragma unroll
      for (int i = 1; i < 8; ++i){ p0 = fmaxf(p0, e0[i]); p1 = fmaxf(p1, e1[i]); }
      p0 = fmaxf(p0, __shfl_xor(p0, 16)); p0 = fmaxf(p0, __shfl_xor(p0, 32));
      p1 = fmaxf(p1, __shfl_xor(p1, 16)); p1 = fmaxf(p1, __shfl_xor(p1, 32));
      if (!__all((p0 - m0 <= 8.0f) && (p1 - m1 <= 8.0f))){
        float mn0 = fmaxf(m0, p0), mn1 = fmaxf(m1, p1);
        float c0 = __expf(m0 - mn0), c1 = __expf(m1 - mn1);
        l0 *= c0; l1 *= c1;
        #pragma unroll
        for (int df = 0; df < 16; ++df){ o[df][0] *= c0; o[df][1] *= c1; }
        m0 = mn0; m1 = mn1;
      }
      float ps0 = 0.f, ps1 = 0.f;
      #pragma unroll
      for (int i = 0; i < 8; ++i){
        e0[i] = __expf(e0[i] - m0); ps0 += e0[i];
        e1[i] = __expf(e1[i] - m1); ps1 += e1[i];
      }
      ps0 += __shfl_xor(ps0, 16); ps0 += __shfl_xor(ps0, 32);
      ps1 += __shfl_xor(ps1, 16); ps1 += __shfl_xor(ps1, 32);
      l0 += ps0; l1 += ps1;

      bf16x8 pf[2];
      #pragma unroll
      for (int q2 = 0; q2 < 2; ++q2){
        const float* e = (q2 == 0) ? e0 : e1;
        unsigned A0 = pack2bf(e[0], e[1]), B0 = pack2bf(e[2], e[3]);
        unsigned A1 = pack2bf(e[4], e[5]), B1 = pack2bf(e[6], e[7]);
        unsigned x0 = __shfl(A0, laneA), x1 = __shfl(B0, laneA);
        unsigned x2 = __shfl(A1, laneA), x3 = __shfl(B1, laneA);
        unsigned y0 = __shfl(A0, laneA + 16), y1 = __shfl(B0, laneA + 16);
        unsigned y2 = __shfl(A1, laneA + 16), y3 = __shfl(B1, laneA + 16);
        union { unsigned u[4]; bf16x8 v; } r;
        r.u[0] = tf1 ? x2 : x0; r.u[1] = tf1 ? x3 : x1;
        r.u[2] = tf1 ? y2 : y0; r.u[3] = tf1 ? y3 : y1;
        pf[q2] = r.v;
      }

      __builtin_amdgcn_s_setprio(1);
      #pragma unroll
      for (int df = 0; df < 16; ++df){
        const int d   = (df << 4) + li;
        const int row = d >> 1;
        bf16x8 va = *(const bf16x8*)(vb + (row << 7) + ((d & 1) << 6) + (((g ^ row) & 3) << 4));
        o[df][0] = __builtin_amdgcn_mfma_f32_16x16x32_bf16(va, pf[0], o[df][0], 0, 0, 0);
        o[df][1] = __builtin_amdgcn_mfma_f32_16x16x32_bf16(va, pf[1], o[df][1], 0, 0, 0);
      }
      __builtin_amdgcn_s_setprio(0);
    }
  }
  __syncthreads();

  float iv0 = 1.0f / l0, iv1 = 1.0f / l1;
  #pragma unroll
  for (int df = 0; df < 16; ++df){ o[df][0] *= iv0; o[df][1] *= iv1; }

  char* const OT = smem + (wid << 13);     // 8 waves x 8KB = 64KB
  const int b = bh >> 2, h = bh & 3;
  #pragma unroll
  for (int q2 = 0; q2 < 2; ++q2){
    #pragma unroll
    for (int df = 0; df < 16; ++df){
      f32x4 c = o[df][q2];
      uint2 pk; pk.x = pack2bf(c[0], c[1]); pk.y = pack2bf(c[2], c[3]);
      const int addr = (li << 9) + (((df << 5) + (g << 3)) ^ ((li & 7) << 4));
      *(uint2*)(OT + addr) = pk;
    }
    __asm__ volatile("s_waitcnt lgkmcnt(0)" ::: "memory");
    __builtin_amdgcn_sched_barrier(0);
    #pragma unroll
    for (int p = 0; p < 8; ++p){
      const int idx = (p << 6) + lane;
      const int row = idx >> 5, c16 = idx & 31;
      uint4 vv = *(const uint4*)(OT + (row << 9) + (((c16 << 4)) ^ ((row & 7) << 4)));
      const int q = q0 + (q2 << 4) + row;
      *(uint4*)(Ow + ((size_t)((b << 9) + q)) * 1024 + (h << 8) + (c16 << 3)) = vv;
    }
    __asm__ volatile("s_waitcnt lgkmcnt(0)" ::: "memory");
    __builtin_amdgcn_sched_barrier(0);
  }
}

// ---------------------------------------------------------------------------
// K4: patch attention v2 — batched heads, shuffle-P, 2 fences per token.
// ---------------------------------------------------------------------------
__global__ __launch_bounds__(256) void k_patch2(
    const float* __restrict__ x1,
    const unsigned short* __restrict__ Wp,
    const float* __restrict__ bqc, const float* __restrict__ bkc,
    const float* __restrict__ bvl, const float* __restrict__ blo,
    unsigned short* __restrict__ yb)
{
  extern __shared__ char lds[];
  const int tid = threadIdx.x;
  const int wid = tid >> 6, lane = tid & 63;
  const int g = lane >> 4, li = lane & 15;
  const int n = (blockIdx.x << 2) + wid;

  char* const QB = lds + (wid << 14);
  char* const KB = QB + 4096;
  char* const VB = QB + 8192;
  const int swz = (li & 7) << 4;
  const bf16x8 zf = (bf16x8){0,0,0,0,0,0,0,0};

  bf16x8 xf = zf;
  if (g < 2){
    const float* xr = x1 + (size_t)n * 256 + li * 16 + g * 8;
    float4 a = *(const float4*)xr;
    float4 b = *(const float4*)(xr + 4);
    xf = pack8(a.x,a.y,a.z,a.w, b.x,b.y,b.z,b.w);
  }

  #pragma unroll
  for (int m = 0; m < 3; ++m){
    const float* bias = (m == 0) ? bqc : ((m == 1) ? bkc : bvl);
    #pragma unroll
    for (int nc = 0; nc < 8; ++nc){
      bf16x8 wf = *(const bf16x8*)(Wp + ((((m << 3) + nc) << 6) + lane) * 8);
      f32x4 c = __builtin_amdgcn_mfma_f32_16x16x32_bf16(xf, wf, (f32x4){0,0,0,0}, 0, 0, 0);
      float bv = bias[(nc << 4) + li];
      if (m < 2){
        char* B = (m == 0) ? QB : KB;
        #pragma unroll
        for (int r = 0; r < 4; ++r){
          int p = (g << 2) + r;
          *(unsigned short*)(B + (p << 8) + (((((nc << 4) + li) << 1)) ^ ((p & 7) << 4))) = f2bf(c[r] + bv);
        }
      } else {
        int cc = (nc << 4) + li;
        *(unsigned*)(VB + cc * 48 + (g << 3))     = pack2bf(c[0] + bv, c[1] + bv);
        *(unsigned*)(VB + cc * 48 + (g << 3) + 4) = pack2bf(c[2] + bv, c[3] + bv);
      }
    }
  }
  __asm__ volatile("s_waitcnt lgkmcnt(0)" ::: "memory");
  __builtin_amdgcn_sched_barrier(0);

  f32x4 st[4];
  #pragma unroll
  for (int h = 0; h < 4; ++h){
    const int cb = (h << 6) + (g << 4);
    bf16x8 kf = *(const bf16x8*)(KB + (li << 8) + (cb ^ swz));
    bf16x8 qf = *(const bf16x8*)(QB + (li << 8) + (cb ^ swz));
    st[h] = __builtin_amdgcn_mfma_f32_16x16x32_bf16(kf, qf, (f32x4){0,0,0,0}, 0, 0, 0);
  }

  float e[4][4];
  #pragma unroll
  for (int h = 0; h < 4; ++h){
    float s0 = st[h][0]*0.0625f, s1 = st[h][1]*0.0625f,
          s2 = st[h][2]*0.0625f, s3 = st[h][3]*0.0625f;
    float mx = fmaxf(fmaxf(s0, s1), fmaxf(s2, s3));
    mx = fmaxf(mx, __shfl_xor(mx, 16));
    mx = fmaxf(mx, __shfl_xor(mx, 32));
    float v0 = __expf(s0-mx), v1 = __expf(s1-mx), v2 = __expf(s2-mx), v3 = __expf(s3-mx);
    float ss = v0 + v1 + v2 + v3;
    ss += __shfl_xor(ss, 16);
    ss += __shfl_xor(ss, 32);
    float inv = 1.0f / ss;
    e[h][0] = v0*inv; e[h][1] = v1*inv; e[h][2] = v2*inv; e[h][3] = v3*inv;
  }

  const int laneA = ((g & 1) << 5) + li;
  f32x4 of[8];
  #pragma unroll
  for (int i = 0; i < 8; ++i) of[i] = (f32x4){0,0,0,0};
  #pragma unroll
  for (int h = 0; h < 4; ++h){
    unsigned pk0 = pack2bf(e[h][0], e[h][1]);
    unsigned pk1 = pack2bf(e[h][2], e[h][3]);
    unsigned u0 = __shfl(pk0, laneA),      u1 = __shfl(pk1, laneA);
    unsigned u2 = __shfl(pk0, laneA + 16), u3 = __shfl(pk1, laneA + 16);
    union { unsigned u[4]; bf16x8 v; } pr;
    pr.u[0] = u0; pr.u[1] = u1; pr.u[2] = u2; pr.u[3] = u3;
    bf16x8 pf = (g < 2) ? pr.v : zf;
    #pragma unroll
    for (int t = 0; t < 2; ++t){
      bf16x8 vf = zf;
      if (g < 2) vf = *(const bf16x8*)(VB + ((h << 5) + (t << 4) + li) * 48 + (g << 4));
      of[(h << 1) + t] = __builtin_amdgcn_mfma_f32_16x16x32_bf16(pf, vf, of[(h << 1) + t], 0, 0, 0);
    }
  }

  __asm__ volatile("s_waitcnt lgkmcnt(0)" ::: "memory");
  __builtin_amdgcn_sched_barrier(0);
  #pragma unroll
  for (int h = 0; h < 4; ++h)
    #pragma unroll
    for (int t = 0; t < 2; ++t){
      f32x4 c = of[(h << 1) + t];
      int cc = (h << 5) + (t << 4) + li;
      #pragma unroll
      for (int r = 0; r < 4; ++r){
        int p = (g << 2) + r;
        *(unsigned short*)(KB + (p << 8) + ((cc << 1) ^ ((p & 7) << 4))) = f2bf(c[r]);
      }
    }
  __asm__ volatile("s_waitcnt lgkmcnt(0)" ::: "memory");
  __builtin_amdgcn_sched_barrier(0);

  f32x4 y = (f32x4){0,0,0,0};
  #pragma unroll
  for (int kc = 0; kc < 4; ++kc){
    bf16x8 af = *(const bf16x8*)(KB + (li << 8) + ((((kc << 6) + (g << 4))) ^ swz));
    bf16x8 wf = *(const bf16x8*)(Wp + (((24 + kc) << 6) + lane) * 8);
    y = __builtin_amdgcn_mfma_f32_16x16x32_bf16(af, wf, y, 0, 0, 0);
  }
  float bv = blo[li];
  unsigned short* yr = yb + (size_t)n * 256 + li;
  #pragma unroll
  for (int r = 0; r < 4; ++r)
    yr[((g << 2) + r) << 4] = f2bf(y[r] + bv);
}

// ---------------------------------------------------------------------------
extern "C" void kernel_launch(void* const* d_in, const int* in_sizes, int n_in,
                              void* d_out, int out_size, void* d_ws, size_t ws_size,
                              hipStream_t stream)
{
  const float* x     = (const float*)d_in[0];
  const float* Wq    = (const float*)d_in[1];
  const float* bq    = (const float*)d_in[2];
  const float* Wk    = (const float*)d_in[3];
  const float* bk    = (const float*)d_in[4];
  const float* Wv    = (const float*)d_in[5];
  const float* bv    = (const float*)d_in[6];
  const float* Wlin1 = (const float*)d_in[7];
  const float* blin1 = (const float*)d_in[8];
  const float* Wqc   = (const float*)d_in[9];
  const float* bqc   = (const float*)d_in[10];
  const float* Wkc   = (const float*)d_in[11];
  const float* bkc   = (const float*)d_in[12];
  const float* Wvl   = (const float*)d_in[13];
  const float* bvl   = (const float*)d_in[14];
  const float* Wlo   = (const float*)d_in[15];
  const float* blo   = (const float*)d_in[16];
  const float* Wlout = (const float*)d_in[17];
  const float* blout = (const float*)d_in[18];
  float* out = (float*)d_out;

  char* w = (char*)d_ws;
  unsigned short* Qw  = (unsigned short*)w;
  unsigned short* yb  = (unsigned short*)w;
  unsigned short* Kw  = (unsigned short*)(w + 33554432);
  unsigned short* xb  = (unsigned short*)(w + 100663296);
  unsigned short* Ow  = (unsigned short*)(w + 100663296);
  unsigned short* Vtw = (unsigned short*)(w + 134217728);
  float* x1     = (float*)(w + 150994944);
  unsigned short* Wqkvb  = (unsigned short*)(w + 167772160);
  unsigned short* Wlin1b = (unsigned short*)(w + 169345024);
  unsigned short* Wloutb = (unsigned short*)(w + 169869312);
  unsigned short* Wp     = (unsigned short*)(w + 170000384);

  hipFuncSetAttribute((const void*)k_attn, hipFuncAttributeMaxDynamicSharedMemorySize, 131072);
  hipFuncSetAttribute((const void*)k_gemm<0>, hipFuncAttributeMaxDynamicSharedMemorySize, 65536);
  hipFuncSetAttribute((const void*)k_gemm_ln, hipFuncAttributeMaxDynamicSharedMemorySize, 40960);
  hipFuncSetAttribute((const void*)k_patch2, hipFuncAttributeMaxDynamicSharedMemorySize, 65536);

  // ---- prep ----
  k_cvt<<<4096, 256, 0, stream>>>(x, xb, 1048576);
  k_cvt<<<256, 256, 0, stream>>>(Wq, Wqkvb, 65536);
  k_cvt<<<256, 256, 0, stream>>>(Wk, Wqkvb + 262144, 65536);
  k_cvt<<<256, 256, 0, stream>>>(Wv, Wqkvb + 524288, 65536);
  k_cvt<<<256, 256, 0, stream>>>(Wlin1, Wlin1b, 65536);
  k_cvt<<<64, 256, 0, stream>>>(Wlout, Wloutb, 16384);
  k_packw<<<7, 256, 0, stream>>>(Wqc, Wkc, Wvl, Wlo, Wp);

  // ---- QKV projection (V written to tiled VtT) ----
  k_gemm<0><<<dim3(128, 24), 256, 65536, stream>>>(xb, Wqkvb, bq, bk, bv,
                                                   Qw, Kw, Vtw, 256);
  k_attn<<<dim3(2, 128), 512, 131072, stream>>>(Qw, Kw, Vtw, Ow);

  // ---- lin1 + fused LN ----
  k_gemm_ln<<<256, 256, 40960, stream>>>(Ow, Wlin1b, blin1, x, x1, 1024);

  // ---- patch attention ----
  k_patch2<<<4096, 256, 65536, stream>>>(x1, Wp, bqc, bkc, bvl, blo, yb);

  // ---- Wlout + fused LN ----
  k_gemm_ln<<<256, 256, 40960, stream>>>(yb, Wloutb, blout, x1, out, 256);
}

// Round 16
// 191.835 us; speedup vs baseline: 1.1290x; 1.1290x over previous
//
#include <hip/hip_runtime.h>
#include <hip/hip_bf16.h>
#include <math.h>

// ---- problem constants ----
// bs=32, S=512, D=256, HS=4 heads (head dim = D = 256!), NT = 16384 tokens
// patch: NP=16 patches x P=16, CC=128, HP=4 heads x CE=32

typedef __attribute__((ext_vector_type(8))) short bf16x8;
typedef __attribute__((ext_vector_type(4))) float f32x4;

__device__ __forceinline__ unsigned short f2bf(float f){
  unsigned u = __float_as_uint(f);
  return (unsigned short)((u + 0x7FFFu + ((u >> 16) & 1u)) >> 16);   // RNE
}
__device__ __forceinline__ unsigned pack2bf(float a, float b){
  return (unsigned)f2bf(a) | ((unsigned)f2bf(b) << 16);
}
__device__ __forceinline__ bf16x8 pack8(float a0,float a1,float a2,float a3,
                                        float a4,float a5,float a6,float a7){
  union { bf16x8 v; unsigned u[4]; } t;
  t.u[0]=pack2bf(a0,a1); t.u[1]=pack2bf(a2,a3);
  t.u[2]=pack2bf(a4,a5); t.u[3]=pack2bf(a6,a7);
  return t.v;
}
// async 16B global->LDS (dest = wave-uniform base + lane*16; SOURCE per-lane)
__device__ __forceinline__ void gld16(const void* g, void* l){
  __builtin_amdgcn_global_load_lds((const __attribute__((address_space(1))) void*)g,
                                   (__attribute__((address_space(3))) void*)l, 16, 0, 0);
}

__device__ __forceinline__ void cvt4(const float* __restrict__ src,
                                     unsigned short* __restrict__ dst, int i){
  float4 v = ((const float4*)src)[i];
  ushort4 o;
  o.x = f2bf(v.x); o.y = f2bf(v.y); o.z = f2bf(v.z); o.w = f2bf(v.w);
  ((ushort4*)dst)[i] = o;
}

// ---------------------------------------------------------------------------
// k_prep_all: all dtype conversions + patch-weight fragment packing, 1 launch.
// segments: x 1048576 | Wq 65536 | Wk 65536 | Wv 65536 | Wlin1 65536 |
//           Wlout 16384 | packw 1792   (total 1328896 = 5191*256)
// ---------------------------------------------------------------------------
__global__ __launch_bounds__(256) void k_prep_all(
    const float* __restrict__ x,
    const float* __restrict__ Wq, const float* __restrict__ Wk,
    const float* __restrict__ Wv, const float* __restrict__ Wlin1,
    const float* __restrict__ Wlout,
    const float* __restrict__ Wqc, const float* __restrict__ Wkc,
    const float* __restrict__ Wvl, const float* __restrict__ Wlo,
    unsigned short* __restrict__ xb, unsigned short* __restrict__ Wqkvb,
    unsigned short* __restrict__ Wlin1b, unsigned short* __restrict__ Wloutb,
    unsigned short* __restrict__ Wp)
{
  int i = blockIdx.x * 256 + threadIdx.x;
  if (i < 1048576){ cvt4(x, xb, i); return; }
  i -= 1048576;
  if (i < 65536){ cvt4(Wq, Wqkvb, i); return; }
  i -= 65536;
  if (i < 65536){ cvt4(Wk, Wqkvb + 262144, i); return; }
  i -= 65536;
  if (i < 65536){ cvt4(Wv, Wqkvb + 524288, i); return; }
  i -= 65536;
  if (i < 65536){ cvt4(Wlin1, Wlin1b, i); return; }
  i -= 65536;
  if (i < 16384){ cvt4(Wlout, Wloutb, i); return; }
  i -= 16384;
  if (i >= 1792) return;
  const int it = i;
  int ch = it >> 6, lane = it & 63;
  int g = lane >> 4, li = lane & 15;
  unsigned short o[8];
  if (ch < 24){
    int m = ch >> 3, nc = ch & 7;
    const float* W = (m == 0) ? Wqc : (m == 1 ? Wkc : Wvl);
    int c = nc * 16 + li;
    #pragma unroll
    for (int j = 0; j < 8; ++j){
      int k = g * 8 + j;
      o[j] = (k < 16) ? f2bf(W[c * 16 + k]) : (unsigned short)0;
    }
  } else {
    int kc = ch - 24;
    #pragma unroll
    for (int j = 0; j < 8; ++j){
      int k = kc * 32 + g * 8 + j;
      o[j] = f2bf(Wlo[li * 128 + k]);
    }
  }
  #pragma unroll
  for (int j = 0; j < 8; ++j) Wp[it * 8 + j] = o[j];
}

// ---------------------------------------------------------------------------
// k_gemm<0>: QKV projection, 128x128 tile, XCD-chunked swizzle.
// Q/K scatter [bh][s][d] bf16; V -> tiled VtT (attn LDS image).
// ---------------------------------------------------------------------------
template<int EPI>
__global__ __launch_bounds__(256) void k_gemm(
    const unsigned short* __restrict__ A,   // [M,K] bf16
    const unsigned short* __restrict__ W,   // [N,K] bf16
    const float* __restrict__ b0,
    const float* __restrict__ b1,
    const float* __restrict__ b2,
    void* __restrict__ outp,
    unsigned short* __restrict__ Kw_,
    unsigned short* __restrict__ Vt_,
    int K)
{
  extern __shared__ char sm[];
  const int tid = threadIdx.x;
  const int wid = tid >> 6, lane = tid & 63;
  const int g = lane >> 4, li = lane & 15;
  const int wm = wid >> 1, wn = wid & 1;
  const int lin = blockIdx.x + (blockIdx.y << 7);
  const int nl2 = ((lin & 7) * 384) + (lin >> 3);
  const int mt  = nl2 / 24;
  const int nt  = nl2 - mt * 24;
  const int m0 = mt << 7, n0 = nt << 7;

  const unsigned short* Ab = A + (size_t)m0 * K;
  const unsigned short* Wb = W + (size_t)n0 * K;

  auto stage = [&](char* dst, const unsigned short* src, int k0){
    #pragma unroll
    for (int r = 0; r < 4; ++r){
      int row = (r << 5) + (tid >> 3);
      int cb  = (tid & 7) << 4;
      int cbs = cb ^ ((row & 7) << 4);
      gld16(src + row * K + k0 + (cbs >> 1), dst + (r << 12) + (wid << 10));
    }
  };

  f32x4 acc[4][4];
  #pragma unroll
  for (int mf = 0; mf < 4; ++mf)
    #pragma unroll
    for (int nf = 0; nf < 4; ++nf) acc[mf][nf] = (f32x4){0.f,0.f,0.f,0.f};

  const int nk = K >> 6;
  stage(sm, Ab, 0); stage(sm + 32768, Wb, 0);
  for (int kt = 0; kt < nk; ++kt){
    char* Acur = (kt & 1) ? (sm + 16384) : sm;
    char* Wcur = (kt & 1) ? (sm + 49152) : (sm + 32768);
    if (kt + 1 < nk){
      char* Anxt = (kt & 1) ? sm : (sm + 16384);
      char* Wnxt = (kt & 1) ? (sm + 32768) : (sm + 49152);
      stage(Anxt, Ab, (kt + 1) << 6);
      stage(Wnxt, Wb, (kt + 1) << 6);
    }
    __syncthreads();
    bf16x8 af[2][4], wf[2][4];
    #pragma unroll
    for (int kk = 0; kk < 2; ++kk){
      #pragma unroll
      for (int mf = 0; mf < 4; ++mf){
        int row  = (wm << 6) + (mf << 4) + li;
        int colb = ((kk << 6) + (g << 4)) ^ ((row & 7) << 4);
        af[kk][mf] = *(const bf16x8*)(Acur + (row << 7) + colb);
      }
      #pragma unroll
      for (int nf = 0; nf < 4; ++nf){
        int row  = (wn << 6) + (nf << 4) + li;
        int colb = ((kk << 6) + (g << 4)) ^ ((row & 7) << 4);
        wf[kk][nf] = *(const bf16x8*)(Wcur + (row << 7) + colb);
      }
    }
    #pragma unroll
    for (int kk = 0; kk < 2; ++kk)
      #pragma unroll
      for (int mf = 0; mf < 4; ++mf)
        #pragma unroll
        for (int nf = 0; nf < 4; ++nf)
          acc[mf][nf] = __builtin_amdgcn_mfma_f32_16x16x32_bf16(af[kk][mf], wf[kk][nf], acc[mf][nf], 0, 0, 0);
    __syncthreads();
  }

  const int chunk = n0 >> 10;
  const float* bias = (chunk == 0) ? b0 : (chunk == 1 ? b1 : b2);
  const int nq0 = n0 & 1023;
  const int h = nq0 >> 8;                 // uniform per block
  if (chunk == 2){
    const int b  = m0 >> 9;
    const int bh = (b << 2) + h;
    const int d0g = (nq0 & 255) + (wn << 6);
    const int s0g = (m0 & 511) + (wm << 6);
    char* const TB = sm + (wid << 13);     // 8KB per wave
    #pragma unroll
    for (int nf = 0; nf < 4; ++nf){
      const int dloc = (nf << 4) + li;
      const float bv = bias[nq0 + (wn << 6) + (nf << 4) + li];
      #pragma unroll
      for (int mf = 0; mf < 4; ++mf){
        ushort4 pk;
        pk.x = f2bf(acc[mf][nf][0] + bv); pk.y = f2bf(acc[mf][nf][1] + bv);
        pk.z = f2bf(acc[mf][nf][2] + bv); pk.w = f2bf(acc[mf][nf][3] + bv);
        const int unit = ((mf << 2) + g) ^ (dloc & 7);
        *(ushort4*)(TB + (dloc << 7) + (unit << 3)) = pk;
      }
    }
    __asm__ volatile("s_waitcnt lgkmcnt(0)" ::: "memory");
    __builtin_amdgcn_sched_barrier(0);
    #pragma unroll
    for (int p = 0; p < 8; ++p){
      const int dl = (p << 3) + (lane >> 3);
      const int u0 = (lane & 7) << 1;
      uint2 ua = *(const uint2*)(TB + (dl << 7) + (((u0)     ^ (dl & 7)) << 3));
      uint2 ub = *(const uint2*)(TB + (dl << 7) + (((u0 + 1) ^ (dl & 7)) << 3));
      uint4 vv; vv.x = ua.x; vv.y = ua.y; vv.z = ub.x; vv.w = ub.y;
      const int dglob = d0g + dl;
      const int sglb  = s0g + ((lane & 7) << 3);     // 8-aligned
      const int tt    = sglb >> 5;
      const int sc    = (sglb & 31) >> 3;            // s-chunk 0..3
      const int row   = dglob >> 1;
      char* vdst = (char*)Vt_ + ((size_t)bh << 18) + (tt << 14) + (row << 7)
                 + ((dglob & 1) << 6) + ((sc ^ (row & 3)) << 4);
      *(uint4*)vdst = vv;
    }
  } else {
    unsigned short* dst = (chunk == 0) ? (unsigned short*)outp : Kw_;
    #pragma unroll
    for (int nf = 0; nf < 4; ++nf){
      const int nq = nq0 + (wn << 6) + (nf << 4) + li;
      const int d = nq & 255;
      const float bv = bias[nq];
      #pragma unroll
      for (int mf = 0; mf < 4; ++mf){
        const int mbase = m0 + (wm << 6) + (mf << 4) + (g << 2);
        #pragma unroll
        for (int r = 0; r < 4; ++r){
          const int m = mbase + r;
          const int b = m >> 9, s = m & 511;
          dst[(size_t)((((b << 2) + h) << 9) + s) * 256 + d] = f2bf(acc[mf][nf][r] + bv);
        }
      }
    }
  }
}

// ---------------------------------------------------------------------------
// k_gemm_ln: out = LN(A @ W^T + bias + resid). 64x256 tile, BK=32, 4 waves.
// ---------------------------------------------------------------------------
__global__ __launch_bounds__(256) void k_gemm_ln(
    const unsigned short* __restrict__ A,   // [M,K] bf16
    const unsigned short* __restrict__ W,   // [256,K] bf16
    const float* __restrict__ bias,
    const float* __restrict__ resid,        // f32 [M,256]
    float* __restrict__ outp,               // f32 [M,256]
    int K)
{
  extern __shared__ char sm[];
  const int tid = threadIdx.x;
  const int wid = tid >> 6, lane = tid & 63;
  const int g = lane >> 4, li = lane & 15;
  const int m0 = blockIdx.x << 6;
  const unsigned short* Ab = A + (size_t)m0 * K;

  auto stageA = [&](char* dst, int k0){
    int row = tid >> 2;
    int cs  = (tid & 3) ^ (row & 3);
    gld16(Ab + (size_t)row * K + k0 + (cs << 3), dst + (wid << 10));
  };
  auto stageW = [&](char* dst, int k0){
    #pragma unroll
    for (int cc = 0; cc < 4; ++cc){
      int u = (cc << 8) + tid;
      int row = u >> 2;
      int cs  = (u & 3) ^ (row & 3);
      gld16(W + (size_t)row * K + k0 + (cs << 3), dst + (cc << 12) + (wid << 10));
    }
  };

  f32x4 acc[4][4];
  #pragma unroll
  for (int mf = 0; mf < 4; ++mf)
    #pragma unroll
    for (int nf = 0; nf < 4; ++nf) acc[mf][nf] = (f32x4){0.f,0.f,0.f,0.f};

  const int nk = K >> 5;
  stageA(sm, 0); stageW(sm + 8192, 0);
  for (int kt = 0; kt < nk; ++kt){
    char* Acur = (kt & 1) ? (sm + 4096)  : sm;
    char* Wcur = (kt & 1) ? (sm + 24576) : (sm + 8192);
    if (kt + 1 < nk){
      stageA((kt & 1) ? sm : (sm + 4096), (kt + 1) << 5);
      stageW((kt & 1) ? (sm + 8192) : (sm + 24576), (kt + 1) << 5);
    }
    __syncthreads();
    bf16x8 af[4], wf[4];
    #pragma unroll
    for (int mf = 0; mf < 4; ++mf){
      int row  = (mf << 4) + li;
      int colb = (g << 4) ^ ((row & 3) << 4);
      af[mf] = *(const bf16x8*)(Acur + (row << 6) + colb);
    }
    #pragma unroll
    for (int nf = 0; nf < 4; ++nf){
      int row  = (wid << 6) + (nf << 4) + li;
      int colb = (g << 4) ^ ((row & 3) << 4);
      wf[nf] = *(const bf16x8*)(Wcur + (row << 6) + colb);
    }
    #pragma unroll
    for (int mf = 0; mf < 4; ++mf)
      #pragma unroll
      for (int nf = 0; nf < 4; ++nf)
        acc[mf][nf] = __builtin_amdgcn_mfma_f32_16x16x32_bf16(af[mf], wf[nf], acc[mf][nf], 0, 0, 0);
    __syncthreads();
  }

  float bv[4];
  #pragma unroll
  for (int nf = 0; nf < 4; ++nf) bv[nf] = bias[(wid << 6) + (nf << 4) + li];
  #pragma unroll
  for (int mf = 0; mf < 4; ++mf)
    #pragma unroll
    for (int r = 0; r < 4; ++r){
      const int m = (mf << 4) + (g << 2) + r;
      #pragma unroll
      for (int nf = 0; nf < 4; ++nf)
        acc[mf][nf][r] += bv[nf] + resid[(size_t)(m0 + m) * 256 + (wid << 6) + (nf << 4) + li];
    }

  float2* tbl = (float2*)sm;
  #pragma unroll
  for (int mf = 0; mf < 4; ++mf)
    #pragma unroll
    for (int r = 0; r < 4; ++r){
      float ps = 0.f, pq = 0.f;
      #pragma unroll
      for (int nf = 0; nf < 4; ++nf){
        float v = acc[mf][nf][r];
        ps += v; pq += v * v;
      }
      #pragma unroll
      for (int mk = 1; mk <= 8; mk <<= 1){
        ps += __shfl_xor(ps, mk); pq += __shfl_xor(pq, mk);
      }
      if (li == 0){
        float2 e; e.x = ps; e.y = pq;
        tbl[(wid << 6) + (mf << 4) + (g << 2) + r] = e;
      }
    }
  __syncthreads();
  #pragma unroll
  for (int mf = 0; mf < 4; ++mf)
    #pragma unroll
    for (int r = 0; r < 4; ++r){
      const int m = (mf << 4) + (g << 2) + r;
      float s = 0.f, q = 0.f;
      #pragma unroll
      for (int w = 0; w < 4; ++w){
        float2 e = tbl[(w << 6) + m];
        s += e.x; q += e.y;
      }
      float mean = s * (1.0f / 256.0f);
      float inv  = rsqrtf((q - 256.0f * mean * mean) * (1.0f / 255.0f));
      #pragma unroll
      for (int nf = 0; nf < 4; ++nf)
        outp[(size_t)(m0 + m) * 256 + (wid << 6) + (nf << 4) + li] =
            (acc[mf][nf][r] - mean) * inv;
    }
}

// ---------------------------------------------------------------------------
// K2: MFMA flash attention v8 (reverted from v9). 8 waves x 32 q = 256 q/block,
// grid (2,128). KVBLK=32 dbuf 64KB -> 2 blocks/CU capacity.
// ---------------------------------------------------------------------------
__global__ __launch_bounds__(512, 2) void k_attn(const unsigned short* __restrict__ Qw,
                                                 const unsigned short* __restrict__ Kw,
                                                 const unsigned short* __restrict__ Vt,
                                                 unsigned short* __restrict__ Ow)
{
  extern __shared__ char smem[];
  const int tid  = threadIdx.x;
  const int wid  = tid >> 6, lane = tid & 63;
  const int g    = lane >> 4, li = lane & 15;
  const int dd   = blockIdx.x + (blockIdx.y << 1);
  const int nl   = ((dd & 7) << 5) + (dd >> 3);
  const int bh   = nl >> 1;
  const int sblk = (nl & 1) << 8;              // 256 q per block
  const int q0   = sblk + (wid << 5);          // 32 q per wave

  char* const KB0 = smem;            // 2 x 16KB
  char* const VB0 = smem + 32768;    // 2 x 16KB

  auto stageK = [&](char* kbuf, int t0){
    const unsigned short* base = Kw + ((size_t)(bh << 9) + t0 + (wid << 2)) * 256;
    char* dst = kbuf + (wid << 11);
    #pragma unroll
    for (int c = 0; c < 2; ++c){
      int r  = (c << 1) + (lane >> 5);                // 0..3 local
      int s7 = ((wid & 1) << 2) + r;                  // tile-row & 7
      int cs = ((((lane & 31) << 4) ^ (s7 << 4)) >> 1);
      gld16(base + (r << 8) + cs, dst + (c << 10));
    }
  };
  auto stageV = [&](char* vbuf, int tt){
    const char* src = (const char*)Vt + ((size_t)bh << 18) + ((size_t)tt << 14)
                    + (wid << 11) + (lane << 4);
    char* dst = vbuf + (wid << 11);
    #pragma unroll
    for (int c = 0; c < 2; ++c)
      gld16(src + (c << 10), dst + (c << 10));
  };

  bf16x8 qf[2][8];
  #pragma unroll
  for (int q2 = 0; q2 < 2; ++q2){
    const unsigned short* qp = Qw + ((size_t)(bh << 9) + q0 + (q2 << 4) + li) * 256 + (g << 3);
    #pragma unroll
    for (int kk = 0; kk < 8; ++kk)
      qf[q2][kk] = *(const bf16x8*)(qp + (kk << 5));
  }
  stageK(KB0, 0);
  stageV(VB0, 0);

  f32x4 o[16][2];
  #pragma unroll
  for (int df = 0; df < 16; ++df){
    o[df][0] = (f32x4){0.f,0.f,0.f,0.f};
    o[df][1] = (f32x4){0.f,0.f,0.f,0.f};
  }
  float m0 = -3.0e38f, m1 = -3.0e38f, l0 = 0.f, l1 = 0.f;

  const float inv256 = 1.0f / 256.0f;
  const int key   = (li & 7) << 4;
  const int laneA = ((g & 1) << 5) + li;
  const bool tf1  = (g >> 1);

  #pragma unroll 1
  for (int t = 0; t < 16; ++t){
    __syncthreads();
    char* kb = KB0 + ((t & 1) << 14);
    char* vb = VB0 + ((t & 1) << 14);
    if (t < 15){
      stageK(KB0 + (((t + 1) & 1) << 14), (t + 1) << 5);
      stageV(VB0 + (((t + 1) & 1) << 14), t + 1);
    }

    f32x4 st[2][2];
    st[0][0] = (f32x4){0,0,0,0}; st[0][1] = (f32x4){0,0,0,0};
    st[1][0] = (f32x4){0,0,0,0}; st[1][1] = (f32x4){0,0,0,0};
    __builtin_amdgcn_s_setprio(1);
    #pragma unroll
    for (int kk = 0; kk < 8; ++kk){
      const int colb = ((kk << 6) + (g << 4)) ^ key;
      bf16x8 kf0 = *(const bf16x8*)(kb + (li << 9) + colb);
      bf16x8 kf1 = *(const bf16x8*)(kb + ((16 + li) << 9) + colb);
      st[0][0] = __builtin_amdgcn_mfma_f32_16x16x32_bf16(kf0, qf[0][kk], st[0][0], 0, 0, 0);
      st[0][1] = __builtin_amdgcn_mfma_f32_16x16x32_bf16(kf0, qf[1][kk], st[0][1], 0, 0, 0);
      st[1][0] = __builtin_amdgcn_mfma_f32_16x16x32_bf16(kf1, qf[0][kk], st[1][0], 0, 0, 0);
      st[1][1] = __builtin_amdgcn_mfma_f32_16x16x32_bf16(kf1, qf[1][kk], st[1][1], 0, 0, 0);
    }
    __builtin_amdgcn_s_setprio(0);

    float e0[8], e1[8];
    #pragma unroll
    for (int tf = 0; tf < 2; ++tf)
      #pragma unroll
      for (int r = 0; r < 4; ++r){
        e0[tf*4+r] = st[tf][0][r] * inv256;
        e1[tf*4+r] = st[tf][1][r] * inv256;
      }
    float p0 = e0[0], p1 = e1[0];
    #pragma unroll
    for (int i = 1; i < 8; ++i){ p0 = fmaxf(p0, e0[i]); p1 = fmaxf(p1, e1[i]); }
    p0 = fmaxf(p0, __shfl_xor(p0, 16)); p0 = fmaxf(p0, __shfl_xor(p0, 32));
    p1 = fmaxf(p1, __shfl_xor(p1, 16)); p1 = fmaxf(p1, __shfl_xor(p1, 32));
    if (!__all((p0 - m0 <= 8.0f) && (p1 - m1 <= 8.0f))){
      float mn0 = fmaxf(m0, p0), mn1 = fmaxf(m1, p1);
      float c0 = __expf(m0 - mn0), c1 = __expf(m1 - mn1);
      l0 *= c0; l1 *= c1;
      #pragma unroll
      for (int df = 0; df < 16; ++df){ o[df][0] *= c0; o[df][1] *= c1; }
      m0 = mn0; m1 = mn1;
    }
    float ps0 = 0.f, ps1 = 0.f;
    #pragma unroll
    for (int i = 0; i < 8; ++i){
      e0[i] = __expf(e0[i] - m0); ps0 += e0[i];
      e1[i] = __expf(e1[i] - m1); ps1 += e1[i];
    }
    ps0 += __shfl_xor(ps0, 16); ps0 += __shfl_xor(ps0, 32);
    ps1 += __shfl_xor(ps1, 16); ps1 += __shfl_xor(ps1, 32);
    l0 += ps0; l1 += ps1;

    bf16x8 pf[2];
    #pragma unroll
    for (int q2 = 0; q2 < 2; ++q2){
      const float* e = (q2 == 0) ? e0 : e1;
      unsigned A0 = pack2bf(e[0], e[1]), B0 = pack2bf(e[2], e[3]);
      unsigned A1 = pack2bf(e[4], e[5]), B1 = pack2bf(e[6], e[7]);
      unsigned x0 = __shfl(A0, laneA), x1 = __shfl(B0, laneA);
      unsigned x2 = __shfl(A1, laneA), x3 = __shfl(B1, laneA);
      unsigned y0 = __shfl(A0, laneA + 16), y1 = __shfl(B0, laneA + 16);
      unsigned y2 = __shfl(A1, laneA + 16), y3 = __shfl(B1, laneA + 16);
      union { unsigned u[4]; bf16x8 v; } r;
      r.u[0] = tf1 ? x2 : x0; r.u[1] = tf1 ? x3 : x1;
      r.u[2] = tf1 ? y2 : y0; r.u[3] = tf1 ? y3 : y1;
      pf[q2] = r.v;
    }

    __builtin_amdgcn_s_setprio(1);
    #pragma unroll
    for (int df = 0; df < 16; ++df){
      const int d   = (df << 4) + li;
      const int row = d >> 1;
      bf16x8 va = *(const bf16x8*)(vb + (row << 7) + ((d & 1) << 6) + (((g ^ row) & 3) << 4));
      o[df][0] = __builtin_amdgcn_mfma_f32_16x16x32_bf16(va, pf[0], o[df][0], 0, 0, 0);
      o[df][1] = __builtin_amdgcn_mfma_f32_16x16x32_bf16(va, pf[1], o[df][1], 0, 0, 0);
    }
    __builtin_amdgcn_s_setprio(0);
  }
  __syncthreads();

  float iv0 = 1.0f / l0, iv1 = 1.0f / l1;
  #pragma unroll
  for (int df = 0; df < 16; ++df){ o[df][0] *= iv0; o[df][1] *= iv1; }

  char* const OT = smem + (wid << 13);     // 8 waves x 8KB = 64KB
  const int b = bh >> 2, h = bh & 3;
  #pragma unroll
  for (int q2 = 0; q2 < 2; ++q2){
    #pragma unroll
    for (int df = 0; df < 16; ++df){
      f32x4 c = o[df][q2];
      uint2 pk; pk.x = pack2bf(c[0], c[1]); pk.y = pack2bf(c[2], c[3]);
      const int addr = (li << 9) + (((df << 5) + (g << 3)) ^ ((li & 7) << 4));
      *(uint2*)(OT + addr) = pk;
    }
    __asm__ volatile("s_waitcnt lgkmcnt(0)" ::: "memory");
    __builtin_amdgcn_sched_barrier(0);
    #pragma unroll
    for (int p = 0; p < 8; ++p){
      const int idx = (p << 6) + lane;
      const int row = idx >> 5, c16 = idx & 31;
      uint4 vv = *(const uint4*)(OT + (row << 9) + (((c16 << 4)) ^ ((row & 7) << 4)));
      const int q = q0 + (q2 << 4) + row;
      *(uint4*)(Ow + ((size_t)((b << 9) + q)) * 1024 + (h << 8) + (c16 << 3)) = vv;
    }
    __asm__ volatile("s_waitcnt lgkmcnt(0)" ::: "memory");
    __builtin_amdgcn_sched_barrier(0);
  }
}

// ---------------------------------------------------------------------------
// K4: patch attention v2 — batched heads, shuffle-P, 2 fences per token.
// ---------------------------------------------------------------------------
__global__ __launch_bounds__(256) void k_patch2(
    const float* __restrict__ x1,
    const unsigned short* __restrict__ Wp,
    const float* __restrict__ bqc, const float* __restrict__ bkc,
    const float* __restrict__ bvl, const float* __restrict__ blo,
    unsigned short* __restrict__ yb)
{
  extern __shared__ char lds[];
  const int tid = threadIdx.x;
  const int wid = tid >> 6, lane = tid & 63;
  const int g = lane >> 4, li = lane & 15;
  const int n = (blockIdx.x << 2) + wid;

  char* const QB = lds + (wid << 14);
  char* const KB = QB + 4096;
  char* const VB = QB + 8192;
  const int swz = (li & 7) << 4;
  const bf16x8 zf = (bf16x8){0,0,0,0,0,0,0,0};

  bf16x8 xf = zf;
  if (g < 2){
    const float* xr = x1 + (size_t)n * 256 + li * 16 + g * 8;
    float4 a = *(const float4*)xr;
    float4 b = *(const float4*)(xr + 4);
    xf = pack8(a.x,a.y,a.z,a.w, b.x,b.y,b.z,b.w);
  }

  #pragma unroll
  for (int m = 0; m < 3; ++m){
    const float* bias = (m == 0) ? bqc : ((m == 1) ? bkc : bvl);
    #pragma unroll
    for (int nc = 0; nc < 8; ++nc){
      bf16x8 wf = *(const bf16x8*)(Wp + ((((m << 3) + nc) << 6) + lane) * 8);
      f32x4 c = __builtin_amdgcn_mfma_f32_16x16x32_bf16(xf, wf, (f32x4){0,0,0,0}, 0, 0, 0);
      float bv = bias[(nc << 4) + li];
      if (m < 2){
        char* B = (m == 0) ? QB : KB;
        #pragma unroll
        for (int r = 0; r < 4; ++r){
          int p = (g << 2) + r;
          *(unsigned short*)(B + (p << 8) + (((((nc << 4) + li) << 1)) ^ ((p & 7) << 4))) = f2bf(c[r] + bv);
        }
      } else {
        int cc = (nc << 4) + li;
        *(unsigned*)(VB + cc * 48 + (g << 3))     = pack2bf(c[0] + bv, c[1] + bv);
        *(unsigned*)(VB + cc * 48 + (g << 3) + 4) = pack2bf(c[2] + bv, c[3] + bv);
      }
    }
  }
  __asm__ volatile("s_waitcnt lgkmcnt(0)" ::: "memory");
  __builtin_amdgcn_sched_barrier(0);

  f32x4 st[4];
  #pragma unroll
  for (int h = 0; h < 4; ++h){
    const int cb = (h << 6) + (g << 4);
    bf16x8 kf = *(const bf16x8*)(KB + (li << 8) + (cb ^ swz));
    bf16x8 qf = *(const bf16x8*)(QB + (li << 8) + (cb ^ swz));
    st[h] = __builtin_amdgcn_mfma_f32_16x16x32_bf16(kf, qf, (f32x4){0,0,0,0}, 0, 0, 0);
  }

  float e[4][4];
  #pragma unroll
  for (int h = 0; h < 4; ++h){
    float s0 = st[h][0]*0.0625f, s1 = st[h][1]*0.0625f,
          s2 = st[h][2]*0.0625f, s3 = st[h][3]*0.0625f;
    float mx = fmaxf(fmaxf(s0, s1), fmaxf(s2, s3));
    mx = fmaxf(mx, __shfl_xor(mx, 16));
    mx = fmaxf(mx, __shfl_xor(mx, 32));
    float v0 = __expf(s0-mx), v1 = __expf(s1-mx), v2 = __expf(s2-mx), v3 = __expf(s3-mx);
    float ss = v0 + v1 + v2 + v3;
    ss += __shfl_xor(ss, 16);
    ss += __shfl_xor(ss, 32);
    float inv = 1.0f / ss;
    e[h][0] = v0*inv; e[h][1] = v1*inv; e[h][2] = v2*inv; e[h][3] = v3*inv;
  }

  const int laneA = ((g & 1) << 5) + li;
  f32x4 of[8];
  #pragma unroll
  for (int i = 0; i < 8; ++i) of[i] = (f32x4){0,0,0,0};
  #pragma unroll
  for (int h = 0; h < 4; ++h){
    unsigned pk0 = pack2bf(e[h][0], e[h][1]);
    unsigned pk1 = pack2bf(e[h][2], e[h][3]);
    unsigned u0 = __shfl(pk0, laneA),      u1 = __shfl(pk1, laneA);
    unsigned u2 = __shfl(pk0, laneA + 16), u3 = __shfl(pk1, laneA + 16);
    union { unsigned u[4]; bf16x8 v; } pr;
    pr.u[0] = u0; pr.u[1] = u1; pr.u[2] = u2; pr.u[3] = u3;
    bf16x8 pf = (g < 2) ? pr.v : zf;
    #pragma unroll
    for (int t = 0; t < 2; ++t){
      bf16x8 vf = zf;
      if (g < 2) vf = *(const bf16x8*)(VB + ((h << 5) + (t << 4) + li) * 48 + (g << 4));
      of[(h << 1) + t] = __builtin_amdgcn_mfma_f32_16x16x32_bf16(pf, vf, of[(h << 1) + t], 0, 0, 0);
    }
  }

  __asm__ volatile("s_waitcnt lgkmcnt(0)" ::: "memory");
  __builtin_amdgcn_sched_barrier(0);
  #pragma unroll
  for (int h = 0; h < 4; ++h)
    #pragma unroll
    for (int t = 0; t < 2; ++t){
      f32x4 c = of[(h << 1) + t];
      int cc = (h << 5) + (t << 4) + li;
      #pragma unroll
      for (int r = 0; r < 4; ++r){
        int p = (g << 2) + r;
        *(unsigned short*)(KB + (p << 8) + ((cc << 1) ^ ((p & 7) << 4))) = f2bf(c[r]);
      }
    }
  __asm__ volatile("s_waitcnt lgkmcnt(0)" ::: "memory");
  __builtin_amdgcn_sched_barrier(0);

  f32x4 y = (f32x4){0,0,0,0};
  #pragma unroll
  for (int kc = 0; kc < 4; ++kc){
    bf16x8 af = *(const bf16x8*)(KB + (li << 8) + ((((kc << 6) + (g << 4))) ^ swz));
    bf16x8 wf = *(const bf16x8*)(Wp + (((24 + kc) << 6) + lane) * 8);
    y = __builtin_amdgcn_mfma_f32_16x16x32_bf16(af, wf, y, 0, 0, 0);
  }
  float bv = blo[li];
  unsigned short* yr = yb + (size_t)n * 256 + li;
  #pragma unroll
  for (int r = 0; r < 4; ++r)
    yr[((g << 2) + r) << 4] = f2bf(y[r] + bv);
}

// ---------------------------------------------------------------------------
extern "C" void kernel_launch(void* const* d_in, const int* in_sizes, int n_in,
                              void* d_out, int out_size, void* d_ws, size_t ws_size,
                              hipStream_t stream)
{
  const float* x     = (const float*)d_in[0];
  const float* Wq    = (const float*)d_in[1];
  const float* bq    = (const float*)d_in[2];
  const float* Wk    = (const float*)d_in[3];
  const float* bk    = (const float*)d_in[4];
  const float* Wv    = (const float*)d_in[5];
  const float* bv    = (const float*)d_in[6];
  const float* Wlin1 = (const float*)d_in[7];
  const float* blin1 = (const float*)d_in[8];
  const float* Wqc   = (const float*)d_in[9];
  const float* bqc   = (const float*)d_in[10];
  const float* Wkc   = (const float*)d_in[11];
  const float* bkc   = (const float*)d_in[12];
  const float* Wvl   = (const float*)d_in[13];
  const float* bvl   = (const float*)d_in[14];
  const float* Wlo   = (const float*)d_in[15];
  const float* blo   = (const float*)d_in[16];
  const float* Wlout = (const float*)d_in[17];
  const float* blout = (const float*)d_in[18];
  float* out = (float*)d_out;

  char* w = (char*)d_ws;
  unsigned short* Qw  = (unsigned short*)w;
  unsigned short* yb  = (unsigned short*)w;
  unsigned short* Kw  = (unsigned short*)(w + 33554432);
  unsigned short* xb  = (unsigned short*)(w + 100663296);
  unsigned short* Ow  = (unsigned short*)(w + 100663296);
  unsigned short* Vtw = (unsigned short*)(w + 134217728);
  float* x1     = (float*)(w + 150994944);
  unsigned short* Wqkvb  = (unsigned short*)(w + 167772160);
  unsigned short* Wlin1b = (unsigned short*)(w + 169345024);
  unsigned short* Wloutb = (unsigned short*)(w + 169869312);
  unsigned short* Wp     = (unsigned short*)(w + 170000384);

  hipFuncSetAttribute((const void*)k_attn, hipFuncAttributeMaxDynamicSharedMemorySize, 65536);
  hipFuncSetAttribute((const void*)k_gemm<0>, hipFuncAttributeMaxDynamicSharedMemorySize, 65536);
  hipFuncSetAttribute((const void*)k_gemm_ln, hipFuncAttributeMaxDynamicSharedMemorySize, 40960);
  hipFuncSetAttribute((const void*)k_patch2, hipFuncAttributeMaxDynamicSharedMemorySize, 65536);

  // ---- prep (single launch) ----
  k_prep_all<<<5191, 256, 0, stream>>>(x, Wq, Wk, Wv, Wlin1, Wlout,
                                       Wqc, Wkc, Wvl, Wlo,
                                       xb, Wqkvb, Wlin1b, Wloutb, Wp);

  // ---- QKV projection (V written to tiled VtT) ----
  k_gemm<0><<<dim3(128, 24), 256, 65536, stream>>>(xb, Wqkvb, bq, bk, bv,
                                                   Qw, Kw, Vtw, 256);
  k_attn<<<dim3(2, 128), 512, 65536, stream>>>(Qw, Kw, Vtw, Ow);

  // ---- lin1 + fused LN ----
  k_gemm_ln<<<256, 256, 40960, stream>>>(Ow, Wlin1b, blin1, x, x1, 1024);

  // ---- patch attention ----
  k_patch2<<<4096, 256, 65536, stream>>>(x1, Wp, bqc, bkc, bvl, blo, yb);

  // ---- Wlout + fused LN ----
  k_gemm_ln<<<256, 256, 40960, stream>>>(yb, Wloutb, blout, x1, out, 256);
}

// Round 18
// 188.223 us; speedup vs baseline: 1.1506x; 1.0192x over previous
//
#include <hip/hip_runtime.h>
#include <hip/hip_bf16.h>
#include <math.h>

// ---- problem constants ----
// bs=32, S=512, D=256, HS=4 heads (head dim = D = 256!), NT = 16384 tokens
// patch: NP=16 patches x P=16, CC=128, HP=4 heads x CE=32

typedef __attribute__((ext_vector_type(8))) short bf16x8;
typedef __attribute__((ext_vector_type(4))) float f32x4;

__device__ __forceinline__ unsigned short f2bf(float f){
  unsigned u = __float_as_uint(f);
  return (unsigned short)((u + 0x7FFFu + ((u >> 16) & 1u)) >> 16);   // RNE
}
__device__ __forceinline__ float bf2f(unsigned short s){
  return __uint_as_float(((unsigned)s) << 16);
}
__device__ __forceinline__ unsigned pack2bf(float a, float b){
  return (unsigned)f2bf(a) | ((unsigned)f2bf(b) << 16);
}
// async 16B global->LDS (dest = wave-uniform base + lane*16; SOURCE per-lane)
__device__ __forceinline__ void gld16(const void* g, void* l){
  __builtin_amdgcn_global_load_lds((const __attribute__((address_space(1))) void*)g,
                                   (__attribute__((address_space(3))) void*)l, 16, 0, 0);
}

__device__ __forceinline__ void cvt4(const float* __restrict__ src,
                                     unsigned short* __restrict__ dst, int i){
  float4 v = ((const float4*)src)[i];
  ushort4 o;
  o.x = f2bf(v.x); o.y = f2bf(v.y); o.z = f2bf(v.z); o.w = f2bf(v.w);
  ((ushort4*)dst)[i] = o;
}

// ---------------------------------------------------------------------------
// k_prep_all: all dtype conversions + patch-weight fragment packing, 1 launch.
// ---------------------------------------------------------------------------
__global__ __launch_bounds__(256) void k_prep_all(
    const float* __restrict__ x,
    const float* __restrict__ Wq, const float* __restrict__ Wk,
    const float* __restrict__ Wv, const float* __restrict__ Wlin1,
    const float* __restrict__ Wlout,
    const float* __restrict__ Wqc, const float* __restrict__ Wkc,
    const float* __restrict__ Wvl, const float* __restrict__ Wlo,
    unsigned short* __restrict__ xb, unsigned short* __restrict__ Wqkvb,
    unsigned short* __restrict__ Wlin1b, unsigned short* __restrict__ Wloutb,
    unsigned short* __restrict__ Wp)
{
  int i = blockIdx.x * 256 + threadIdx.x;
  if (i < 1048576){ cvt4(x, xb, i); return; }
  i -= 1048576;
  if (i < 65536){ cvt4(Wq, Wqkvb, i); return; }
  i -= 65536;
  if (i < 65536){ cvt4(Wk, Wqkvb + 262144, i); return; }
  i -= 65536;
  if (i < 65536){ cvt4(Wv, Wqkvb + 524288, i); return; }
  i -= 65536;
  if (i < 65536){ cvt4(Wlin1, Wlin1b, i); return; }
  i -= 65536;
  if (i < 16384){ cvt4(Wlout, Wloutb, i); return; }
  i -= 16384;
  if (i >= 1792) return;
  const int it = i;
  int ch = it >> 6, lane = it & 63;
  int g = lane >> 4, li = lane & 15;
  unsigned short o[8];
  if (ch < 24){
    int m = ch >> 3, nc = ch & 7;
    const float* W = (m == 0) ? Wqc : (m == 1 ? Wkc : Wvl);
    int c = nc * 16 + li;
    #pragma unroll
    for (int j = 0; j < 8; ++j){
      int k = g * 8 + j;
      o[j] = (k < 16) ? f2bf(W[c * 16 + k]) : (unsigned short)0;
    }
  } else {
    int kc = ch - 24;
    #pragma unroll
    for (int j = 0; j < 8; ++j){
      int k = kc * 32 + g * 8 + j;
      o[j] = f2bf(Wlo[li * 128 + k]);
    }
  }
  #pragma unroll
  for (int j = 0; j < 8; ++j) Wp[it * 8 + j] = o[j];
}

// ---------------------------------------------------------------------------
// k_gemm<0>: QKV projection, 128x128 tile, XCD-chunked swizzle.
// Q/K scatter [bh][s][d] bf16; V -> tiled VtT (attn LDS image).
// ---------------------------------------------------------------------------
template<int EPI>
__global__ __launch_bounds__(256) void k_gemm(
    const unsigned short* __restrict__ A,   // [M,K] bf16
    const unsigned short* __restrict__ W,   // [N,K] bf16
    const float* __restrict__ b0,
    const float* __restrict__ b1,
    const float* __restrict__ b2,
    void* __restrict__ outp,
    unsigned short* __restrict__ Kw_,
    unsigned short* __restrict__ Vt_,
    int K)
{
  extern __shared__ char sm[];
  const int tid = threadIdx.x;
  const int wid = tid >> 6, lane = tid & 63;
  const int g = lane >> 4, li = lane & 15;
  const int wm = wid >> 1, wn = wid & 1;
  const int lin = blockIdx.x + (blockIdx.y << 7);
  const int nl2 = ((lin & 7) * 384) + (lin >> 3);
  const int mt  = nl2 / 24;
  const int nt  = nl2 - mt * 24;
  const int m0 = mt << 7, n0 = nt << 7;

  const unsigned short* Ab = A + (size_t)m0 * K;
  const unsigned short* Wb = W + (size_t)n0 * K;

  auto stage = [&](char* dst, const unsigned short* src, int k0){
    #pragma unroll
    for (int r = 0; r < 4; ++r){
      int row = (r << 5) + (tid >> 3);
      int cb  = (tid & 7) << 4;
      int cbs = cb ^ ((row & 7) << 4);
      gld16(src + row * K + k0 + (cbs >> 1), dst + (r << 12) + (wid << 10));
    }
  };

  f32x4 acc[4][4];
  #pragma unroll
  for (int mf = 0; mf < 4; ++mf)
    #pragma unroll
    for (int nf = 0; nf < 4; ++nf) acc[mf][nf] = (f32x4){0.f,0.f,0.f,0.f};

  const int nk = K >> 6;
  stage(sm, Ab, 0); stage(sm + 32768, Wb, 0);
  for (int kt = 0; kt < nk; ++kt){
    char* Acur = (kt & 1) ? (sm + 16384) : sm;
    char* Wcur = (kt & 1) ? (sm + 49152) : (sm + 32768);
    if (kt + 1 < nk){
      char* Anxt = (kt & 1) ? sm : (sm + 16384);
      char* Wnxt = (kt & 1) ? (sm + 32768) : (sm + 49152);
      stage(Anxt, Ab, (kt + 1) << 6);
      stage(Wnxt, Wb, (kt + 1) << 6);
    }
    __syncthreads();
    bf16x8 af[2][4], wf[2][4];
    #pragma unroll
    for (int kk = 0; kk < 2; ++kk){
      #pragma unroll
      for (int mf = 0; mf < 4; ++mf){
        int row  = (wm << 6) + (mf << 4) + li;
        int colb = ((kk << 6) + (g << 4)) ^ ((row & 7) << 4);
        af[kk][mf] = *(const bf16x8*)(Acur + (row << 7) + colb);
      }
      #pragma unroll
      for (int nf = 0; nf < 4; ++nf){
        int row  = (wn << 6) + (nf << 4) + li;
        int colb = ((kk << 6) + (g << 4)) ^ ((row & 7) << 4);
        wf[kk][nf] = *(const bf16x8*)(Wcur + (row << 7) + colb);
      }
    }
    #pragma unroll
    for (int kk = 0; kk < 2; ++kk)
      #pragma unroll
      for (int mf = 0; mf < 4; ++mf)
        #pragma unroll
        for (int nf = 0; nf < 4; ++nf)
          acc[mf][nf] = __builtin_amdgcn_mfma_f32_16x16x32_bf16(af[kk][mf], wf[kk][nf], acc[mf][nf], 0, 0, 0);
    __syncthreads();
  }

  const int chunk = n0 >> 10;
  const float* bias = (chunk == 0) ? b0 : (chunk == 1 ? b1 : b2);
  const int nq0 = n0 & 1023;
  const int h = nq0 >> 8;                 // uniform per block
  if (chunk == 2){
    const int b  = m0 >> 9;
    const int bh = (b << 2) + h;
    const int d0g = (nq0 & 255) + (wn << 6);
    const int s0g = (m0 & 511) + (wm << 6);
    char* const TB = sm + (wid << 13);     // 8KB per wave
    #pragma unroll
    for (int nf = 0; nf < 4; ++nf){
      const int dloc = (nf << 4) + li;
      const float bv = bias[nq0 + (wn << 6) + (nf << 4) + li];
      #pragma unroll
      for (int mf = 0; mf < 4; ++mf){
        ushort4 pk;
        pk.x = f2bf(acc[mf][nf][0] + bv); pk.y = f2bf(acc[mf][nf][1] + bv);
        pk.z = f2bf(acc[mf][nf][2] + bv); pk.w = f2bf(acc[mf][nf][3] + bv);
        const int unit = ((mf << 2) + g) ^ (dloc & 7);
        *(ushort4*)(TB + (dloc << 7) + (unit << 3)) = pk;
      }
    }
    __asm__ volatile("s_waitcnt lgkmcnt(0)" ::: "memory");
    __builtin_amdgcn_sched_barrier(0);
    #pragma unroll
    for (int p = 0; p < 8; ++p){
      const int dl = (p << 3) + (lane >> 3);
      const int u0 = (lane & 7) << 1;
      uint2 ua = *(const uint2*)(TB + (dl << 7) + (((u0)     ^ (dl & 7)) << 3));
      uint2 ub = *(const uint2*)(TB + (dl << 7) + (((u0 + 1) ^ (dl & 7)) << 3));
      uint4 vv; vv.x = ua.x; vv.y = ua.y; vv.z = ub.x; vv.w = ub.y;
      const int dglob = d0g + dl;
      const int sglb  = s0g + ((lane & 7) << 3);     // 8-aligned
      const int tt    = sglb >> 5;
      const int sc    = (sglb & 31) >> 3;            // s-chunk 0..3
      const int row   = dglob >> 1;
      char* vdst = (char*)Vt_ + ((size_t)bh << 18) + (tt << 14) + (row << 7)
                 + ((dglob & 1) << 6) + ((sc ^ (row & 3)) << 4);
      *(uint4*)vdst = vv;
    }
  } else {
    unsigned short* dst = (chunk == 0) ? (unsigned short*)outp : Kw_;
    #pragma unroll
    for (int nf = 0; nf < 4; ++nf){
      const int nq = nq0 + (wn << 6) + (nf << 4) + li;
      const int d = nq & 255;
      const float bv = bias[nq];
      #pragma unroll
      for (int mf = 0; mf < 4; ++mf){
        const int mbase = m0 + (wm << 6) + (mf << 4) + (g << 2);
        #pragma unroll
        for (int r = 0; r < 4; ++r){
          const int m = mbase + r;
          const int b = m >> 9, s = m & 511;
          dst[(size_t)((((b << 2) + h) << 9) + s) * 256 + d] = f2bf(acc[mf][nf][r] + bv);
        }
      }
    }
  }
}

// ---------------------------------------------------------------------------
// k_gemm_ln: out = LN(A @ W^T + bias + resid(bf16)). 64x256 tile, BK=32,
// 4 waves. OUT_BF16: 1 -> bf16 output, 0 -> f32 output.
// ---------------------------------------------------------------------------
template<int OUT_BF16>
__global__ __launch_bounds__(256) void k_gemm_ln(
    const unsigned short* __restrict__ A,     // [M,K] bf16
    const unsigned short* __restrict__ W,     // [256,K] bf16
    const float* __restrict__ bias,
    const unsigned short* __restrict__ resid, // bf16 [M,256]
    void* __restrict__ outp,                  // [M,256] bf16 or f32
    int K)
{
  extern __shared__ char sm[];
  const int tid = threadIdx.x;
  const int wid = tid >> 6, lane = tid & 63;
  const int g = lane >> 4, li = lane & 15;
  const int m0 = blockIdx.x << 6;
  const unsigned short* Ab = A + (size_t)m0 * K;

  auto stageA = [&](char* dst, int k0){
    int row = tid >> 2;
    int cs  = (tid & 3) ^ (row & 3);
    gld16(Ab + (size_t)row * K + k0 + (cs << 3), dst + (wid << 10));
  };
  auto stageW = [&](char* dst, int k0){
    #pragma unroll
    for (int cc = 0; cc < 4; ++cc){
      int u = (cc << 8) + tid;
      int row = u >> 2;
      int cs  = (u & 3) ^ (row & 3);
      gld16(W + (size_t)row * K + k0 + (cs << 3), dst + (cc << 12) + (wid << 10));
    }
  };

  f32x4 acc[4][4];
  #pragma unroll
  for (int mf = 0; mf < 4; ++mf)
    #pragma unroll
    for (int nf = 0; nf < 4; ++nf) acc[mf][nf] = (f32x4){0.f,0.f,0.f,0.f};

  const int nk = K >> 5;
  stageA(sm, 0); stageW(sm + 8192, 0);
  for (int kt = 0; kt < nk; ++kt){
    char* Acur = (kt & 1) ? (sm + 4096)  : sm;
    char* Wcur = (kt & 1) ? (sm + 24576) : (sm + 8192);
    if (kt + 1 < nk){
      stageA((kt & 1) ? sm : (sm + 4096), (kt + 1) << 5);
      stageW((kt & 1) ? (sm + 8192) : (sm + 24576), (kt + 1) << 5);
    }
    __syncthreads();
    bf16x8 af[4], wf[4];
    #pragma unroll
    for (int mf = 0; mf < 4; ++mf){
      int row  = (mf << 4) + li;
      int colb = (g << 4) ^ ((row & 3) << 4);
      af[mf] = *(const bf16x8*)(Acur + (row << 6) + colb);
    }
    #pragma unroll
    for (int nf = 0; nf < 4; ++nf){
      int row  = (wid << 6) + (nf << 4) + li;
      int colb = (g << 4) ^ ((row & 3) << 4);
      wf[nf] = *(const bf16x8*)(Wcur + (row << 6) + colb);
    }
    #pragma unroll
    for (int mf = 0; mf < 4; ++mf)
      #pragma unroll
      for (int nf = 0; nf < 4; ++nf)
        acc[mf][nf] = __builtin_amdgcn_mfma_f32_16x16x32_bf16(af[mf], wf[nf], acc[mf][nf], 0, 0, 0);
    __syncthreads();
  }

  float bv[4];
  #pragma unroll
  for (int nf = 0; nf < 4; ++nf) bv[nf] = bias[(wid << 6) + (nf << 4) + li];
  #pragma unroll
  for (int mf = 0; mf < 4; ++mf)
    #pragma unroll
    for (int r = 0; r < 4; ++r){
      const int m = (mf << 4) + (g << 2) + r;
      #pragma unroll
      for (int nf = 0; nf < 4; ++nf)
        acc[mf][nf][r] += bv[nf] +
          bf2f(resid[(size_t)(m0 + m) * 256 + (wid << 6) + (nf << 4) + li]);
    }

  float2* tbl = (float2*)sm;
  #pragma unroll
  for (int mf = 0; mf < 4; ++mf)
    #pragma unroll
    for (int r = 0; r < 4; ++r){
      float ps = 0.f, pq = 0.f;
      #pragma unroll
      for (int nf = 0; nf < 4; ++nf){
        float v = acc[mf][nf][r];
        ps += v; pq += v * v;
      }
      #pragma unroll
      for (int mk = 1; mk <= 8; mk <<= 1){
        ps += __shfl_xor(ps, mk); pq += __shfl_xor(pq, mk);
      }
      if (li == 0){
        float2 e; e.x = ps; e.y = pq;
        tbl[(wid << 6) + (mf << 4) + (g << 2) + r] = e;
      }
    }
  __syncthreads();
  #pragma unroll
  for (int mf = 0; mf < 4; ++mf)
    #pragma unroll
    for (int r = 0; r < 4; ++r){
      const int m = (mf << 4) + (g << 2) + r;
      float s = 0.f, q = 0.f;
      #pragma unroll
      for (int w = 0; w < 4; ++w){
        float2 e = tbl[(w << 6) + m];
        s += e.x; q += e.y;
      }
      float mean = s * (1.0f / 256.0f);
      float inv  = rsqrtf((q - 256.0f * mean * mean) * (1.0f / 255.0f));
      #pragma unroll
      for (int nf = 0; nf < 4; ++nf){
        const size_t idx = (size_t)(m0 + m) * 256 + (wid << 6) + (nf << 4) + li;
        float v = (acc[mf][nf][r] - mean) * inv;
        if (OUT_BF16) ((unsigned short*)outp)[idx] = f2bf(v);
        else          ((float*)outp)[idx] = v;
      }
    }
}

// ---------------------------------------------------------------------------
// K2: MFMA flash attention v8. 8 waves x 32 q = 256 q/block, grid (2,128).
// KVBLK=32 dbuf 64KB.
// ---------------------------------------------------------------------------
__global__ __launch_bounds__(512, 2) void k_attn(const unsigned short* __restrict__ Qw,
                                                 const unsigned short* __restrict__ Kw,
                                                 const unsigned short* __restrict__ Vt,
                                                 unsigned short* __restrict__ Ow)
{
  extern __shared__ char smem[];
  const int tid  = threadIdx.x;
  const int wid  = tid >> 6, lane = tid & 63;
  const int g    = lane >> 4, li = lane & 15;
  const int dd   = blockIdx.x + (blockIdx.y << 1);
  const int nl   = ((dd & 7) << 5) + (dd >> 3);
  const int bh   = nl >> 1;
  const int sblk = (nl & 1) << 8;              // 256 q per block
  const int q0   = sblk + (wid << 5);          // 32 q per wave

  char* const KB0 = smem;            // 2 x 16KB
  char* const VB0 = smem + 32768;    // 2 x 16KB

  auto stageK = [&](char* kbuf, int t0){
    const unsigned short* base = Kw + ((size_t)(bh << 9) + t0 + (wid << 2)) * 256;
    char* dst = kbuf + (wid << 11);
    #pragma unroll
    for (int c = 0; c < 2; ++c){
      int r  = (c << 1) + (lane >> 5);                // 0..3 local
      int s7 = ((wid & 1) << 2) + r;                  // tile-row & 7
      int cs = ((((lane & 31) << 4) ^ (s7 << 4)) >> 1);
      gld16(base + (r << 8) + cs, dst + (c << 10));
    }
  };
  auto stageV = [&](char* vbuf, int tt){
    const char* src = (const char*)Vt + ((size_t)bh << 18) + ((size_t)tt << 14)
                    + (wid << 11) + (lane << 4);
    char* dst = vbuf + (wid << 11);
    #pragma unroll
    for (int c = 0; c < 2; ++c)
      gld16(src + (c << 10), dst + (c << 10));
  };

  bf16x8 qf[2][8];
  #pragma unroll
  for (int q2 = 0; q2 < 2; ++q2){
    const unsigned short* qp = Qw + ((size_t)(bh << 9) + q0 + (q2 << 4) + li) * 256 + (g << 3);
    #pragma unroll
    for (int kk = 0; kk < 8; ++kk)
      qf[q2][kk] = *(const bf16x8*)(qp + (kk << 5));
  }
  stageK(KB0, 0);
  stageV(VB0, 0);

  f32x4 o[16][2];
  #pragma unroll
  for (int df = 0; df < 16; ++df){
    o[df][0] = (f32x4){0.f,0.f,0.f,0.f};
    o[df][1] = (f32x4){0.f,0.f,0.f,0.f};
  }
  float m0 = -3.0e38f, m1 = -3.0e38f, l0 = 0.f, l1 = 0.f;

  const float inv256 = 1.0f / 256.0f;
  const int key   = (li & 7) << 4;
  const int laneA = ((g & 1) << 5) + li;
  const bool tf1  = (g >> 1);

  #pragma unroll 1
  for (int t = 0; t < 16; ++t){
    __syncthreads();
    char* kb = KB0 + ((t & 1) << 14);
    char* vb = VB0 + ((t & 1) << 14);
    if (t < 15){
      stageK(KB0 + (((t + 1) & 1) << 14), (t + 1) << 5);
      stageV(VB0 + (((t + 1) & 1) << 14), t + 1);
    }

    f32x4 st[2][2];
    st[0][0] = (f32x4){0,0,0,0}; st[0][1] = (f32x4){0,0,0,0};
    st[1][0] = (f32x4){0,0,0,0}; st[1][1] = (f32x4){0,0,0,0};
    __builtin_amdgcn_s_setprio(1);
    #pragma unroll
    for (int kk = 0; kk < 8; ++kk){
      const int colb = ((kk << 6) + (g << 4)) ^ key;
      bf16x8 kf0 = *(const bf16x8*)(kb + (li << 9) + colb);
      bf16x8 kf1 = *(const bf16x8*)(kb + ((16 + li) << 9) + colb);
      st[0][0] = __builtin_amdgcn_mfma_f32_16x16x32_bf16(kf0, qf[0][kk], st[0][0], 0, 0, 0);
      st[0][1] = __builtin_amdgcn_mfma_f32_16x16x32_bf16(kf0, qf[1][kk], st[0][1], 0, 0, 0);
      st[1][0] = __builtin_amdgcn_mfma_f32_16x16x32_bf16(kf1, qf[0][kk], st[1][0], 0, 0, 0);
      st[1][1] = __builtin_amdgcn_mfma_f32_16x16x32_bf16(kf1, qf[1][kk], st[1][1], 0, 0, 0);
    }
    __builtin_amdgcn_s_setprio(0);

    float e0[8], e1[8];
    #pragma unroll
    for (int tf = 0; tf < 2; ++tf)
      #pragma unroll
      for (int r = 0; r < 4; ++r){
        e0[tf*4+r] = st[tf][0][r] * inv256;
        e1[tf*4+r] = st[tf][1][r] * inv256;
      }
    float p0 = e0[0], p1 = e1[0];
    #pragma unroll
    for (int i = 1; i < 8; ++i){ p0 = fmaxf(p0, e0[i]); p1 = fmaxf(p1, e1[i]); }
    p0 = fmaxf(p0, __shfl_xor(p0, 16)); p0 = fmaxf(p0, __shfl_xor(p0, 32));
    p1 = fmaxf(p1, __shfl_xor(p1, 16)); p1 = fmaxf(p1, __shfl_xor(p1, 32));
    if (!__all((p0 - m0 <= 8.0f) && (p1 - m1 <= 8.0f))){
      float mn0 = fmaxf(m0, p0), mn1 = fmaxf(m1, p1);
      float c0 = __expf(m0 - mn0), c1 = __expf(m1 - mn1);
      l0 *= c0; l1 *= c1;
      #pragma unroll
      for (int df = 0; df < 16; ++df){ o[df][0] *= c0; o[df][1] *= c1; }
      m0 = mn0; m1 = mn1;
    }
    float ps0 = 0.f, ps1 = 0.f;
    #pragma unroll
    for (int i = 0; i < 8; ++i){
      e0[i] = __expf(e0[i] - m0); ps0 += e0[i];
      e1[i] = __expf(e1[i] - m1); ps1 += e1[i];
    }
    ps0 += __shfl_xor(ps0, 16); ps0 += __shfl_xor(ps0, 32);
    ps1 += __shfl_xor(ps1, 16); ps1 += __shfl_xor(ps1, 32);
    l0 += ps0; l1 += ps1;

    bf16x8 pf[2];
    #pragma unroll
    for (int q2 = 0; q2 < 2; ++q2){
      const float* e = (q2 == 0) ? e0 : e1;
      unsigned A0 = pack2bf(e[0], e[1]), B0 = pack2bf(e[2], e[3]);
      unsigned A1 = pack2bf(e[4], e[5]), B1 = pack2bf(e[6], e[7]);
      unsigned x0 = __shfl(A0, laneA), x1 = __shfl(B0, laneA);
      unsigned x2 = __shfl(A1, laneA), x3 = __shfl(B1, laneA);
      unsigned y0 = __shfl(A0, laneA + 16), y1 = __shfl(B0, laneA + 16);
      unsigned y2 = __shfl(A1, laneA + 16), y3 = __shfl(B1, laneA + 16);
      union { unsigned u[4]; bf16x8 v; } r;
      r.u[0] = tf1 ? x2 : x0; r.u[1] = tf1 ? x3 : x1;
      r.u[2] = tf1 ? y2 : y0; r.u[3] = tf1 ? y3 : y1;
      pf[q2] = r.v;
    }

    __builtin_amdgcn_s_setprio(1);
    #pragma unroll
    for (int df = 0; df < 16; ++df){
      const int d   = (df << 4) + li;
      const int row = d >> 1;
      bf16x8 va = *(const bf16x8*)(vb + (row << 7) + ((d & 1) << 6) + (((g ^ row) & 3) << 4));
      o[df][0] = __builtin_amdgcn_mfma_f32_16x16x32_bf16(va, pf[0], o[df][0], 0, 0, 0);
      o[df][1] = __builtin_amdgcn_mfma_f32_16x16x32_bf16(va, pf[1], o[df][1], 0, 0, 0);
    }
    __builtin_amdgcn_s_setprio(0);
  }
  __syncthreads();

  float iv0 = 1.0f / l0, iv1 = 1.0f / l1;
  #pragma unroll
  for (int df = 0; df < 16; ++df){ o[df][0] *= iv0; o[df][1] *= iv1; }

  char* const OT = smem + (wid << 13);     // 8 waves x 8KB = 64KB
  const int b = bh >> 2, h = bh & 3;
  #pragma unroll
  for (int q2 = 0; q2 < 2; ++q2){
    #pragma unroll
    for (int df = 0; df < 16; ++df){
      f32x4 c = o[df][q2];
      uint2 pk; pk.x = pack2bf(c[0], c[1]); pk.y = pack2bf(c[2], c[3]);
      const int addr = (li << 9) + (((df << 5) + (g << 3)) ^ ((li & 7) << 4));
      *(uint2*)(OT + addr) = pk;
    }
    __asm__ volatile("s_waitcnt lgkmcnt(0)" ::: "memory");
    __builtin_amdgcn_sched_barrier(0);
    #pragma unroll
    for (int p = 0; p < 8; ++p){
      const int idx = (p << 6) + lane;
      const int row = idx >> 5, c16 = idx & 31;
      uint4 vv = *(const uint4*)(OT + (row << 9) + (((c16 << 4)) ^ ((row & 7) << 4)));
      const int q = q0 + (q2 << 4) + row;
      *(uint4*)(Ow + ((size_t)((b << 9) + q)) * 1024 + (h << 8) + (c16 << 3)) = vv;
    }
    __asm__ volatile("s_waitcnt lgkmcnt(0)" ::: "memory");
    __builtin_amdgcn_sched_barrier(0);
  }
}

// ---------------------------------------------------------------------------
// K4: patch attention v2 — batched heads, shuffle-P, 2 fences per token.
// x1 input bf16.
// ---------------------------------------------------------------------------
__global__ __launch_bounds__(256) void k_patch2(
    const unsigned short* __restrict__ x1b,
    const unsigned short* __restrict__ Wp,
    const float* __restrict__ bqc, const float* __restrict__ bkc,
    const float* __restrict__ bvl, const float* __restrict__ blo,
    unsigned short* __restrict__ yb)
{
  extern __shared__ char lds[];
  const int tid = threadIdx.x;
  const int wid = tid >> 6, lane = tid & 63;
  const int g = lane >> 4, li = lane & 15;
  const int n = (blockIdx.x << 2) + wid;

  char* const QB = lds + (wid << 14);
  char* const KB = QB + 4096;
  char* const VB = QB + 8192;
  const int swz = (li & 7) << 4;
  const bf16x8 zf = (bf16x8){0,0,0,0,0,0,0,0};

  bf16x8 xf = zf;
  if (g < 2)
    xf = *(const bf16x8*)(x1b + (size_t)n * 256 + li * 16 + g * 8);

  #pragma unroll
  for (int m = 0; m < 3; ++m){
    const float* bias = (m == 0) ? bqc : ((m == 1) ? bkc : bvl);
    #pragma unroll
    for (int nc = 0; nc < 8; ++nc){
      bf16x8 wf = *(const bf16x8*)(Wp + ((((m << 3) + nc) << 6) + lane) * 8);
      f32x4 c = __builtin_amdgcn_mfma_f32_16x16x32_bf16(xf, wf, (f32x4){0,0,0,0}, 0, 0, 0);
      float bv = bias[(nc << 4) + li];
      if (m < 2){
        char* B = (m == 0) ? QB : KB;
        #pragma unroll
        for (int r = 0; r < 4; ++r){
          int p = (g << 2) + r;
          *(unsigned short*)(B + (p << 8) + (((((nc << 4) + li) << 1)) ^ ((p & 7) << 4))) = f2bf(c[r] + bv);
        }
      } else {
        int cc = (nc << 4) + li;
        *(unsigned*)(VB + cc * 48 + (g << 3))     = pack2bf(c[0] + bv, c[1] + bv);
        *(unsigned*)(VB + cc * 48 + (g << 3) + 4) = pack2bf(c[2] + bv, c[3] + bv);
      }
    }
  }
  __asm__ volatile("s_waitcnt lgkmcnt(0)" ::: "memory");
  __builtin_amdgcn_sched_barrier(0);

  f32x4 st[4];
  #pragma unroll
  for (int h = 0; h < 4; ++h){
    const int cb = (h << 6) + (g << 4);
    bf16x8 kf = *(const bf16x8*)(KB + (li << 8) + (cb ^ swz));
    bf16x8 qf = *(const bf16x8*)(QB + (li << 8) + (cb ^ swz));
    st[h] = __builtin_amdgcn_mfma_f32_16x16x32_bf16(kf, qf, (f32x4){0,0,0,0}, 0, 0, 0);
  }

  float e[4][4];
  #pragma unroll
  for (int h = 0; h < 4; ++h){
    float s0 = st[h][0]*0.0625f, s1 = st[h][1]*0.0625f,
          s2 = st[h][2]*0.0625f, s3 = st[h][3]*0.0625f;
    float mx = fmaxf(fmaxf(s0, s1), fmaxf(s2, s3));
    mx = fmaxf(mx, __shfl_xor(mx, 16));
    mx = fmaxf(mx, __shfl_xor(mx, 32));
    float v0 = __expf(s0-mx), v1 = __expf(s1-mx), v2 = __expf(s2-mx), v3 = __expf(s3-mx);
    float ss = v0 + v1 + v2 + v3;
    ss += __shfl_xor(ss, 16);
    ss += __shfl_xor(ss, 32);
    float inv = 1.0f / ss;
    e[h][0] = v0*inv; e[h][1] = v1*inv; e[h][2] = v2*inv; e[h][3] = v3*inv;
  }

  const int laneA = ((g & 1) << 5) + li;
  f32x4 of[8];
  #pragma unroll
  for (int i = 0; i < 8; ++i) of[i] = (f32x4){0,0,0,0};
  #pragma unroll
  for (int h = 0; h < 4; ++h){
    unsigned pk0 = pack2bf(e[h][0], e[h][1]);
    unsigned pk1 = pack2bf(e[h][2], e[h][3]);
    unsigned u0 = __shfl(pk0, laneA),      u1 = __shfl(pk1, laneA);
    unsigned u2 = __shfl(pk0, laneA + 16), u3 = __shfl(pk1, laneA + 16);
    union { unsigned u[4]; bf16x8 v; } pr;
    pr.u[0] = u0; pr.u[1] = u1; pr.u[2] = u2; pr.u[3] = u3;
    bf16x8 pf = (g < 2) ? pr.v : zf;
    #pragma unroll
    for (int t = 0; t < 2; ++t){
      bf16x8 vf = zf;
      if (g < 2) vf = *(const bf16x8*)(VB + ((h << 5) + (t << 4) + li) * 48 + (g << 4));
      of[(h << 1) + t] = __builtin_amdgcn_mfma_f32_16x16x32_bf16(pf, vf, of[(h << 1) + t], 0, 0, 0);
    }
  }

  __asm__ volatile("s_waitcnt lgkmcnt(0)" ::: "memory");
  __builtin_amdgcn_sched_barrier(0);
  #pragma unroll
  for (int h = 0; h < 4; ++h)
    #pragma unroll
    for (int t = 0; t < 2; ++t){
      f32x4 c = of[(h << 1) + t];
      int cc = (h << 5) + (t << 4) + li;
      #pragma unroll
      for (int r = 0; r < 4; ++r){
        int p = (g << 2) + r;
        *(unsigned short*)(KB + (p << 8) + ((cc << 1) ^ ((p & 7) << 4))) = f2bf(c[r]);
      }
    }
  __asm__ volatile("s_waitcnt lgkmcnt(0)" ::: "memory");
  __builtin_amdgcn_sched_barrier(0);

  f32x4 y = (f32x4){0,0,0,0};
  #pragma unroll
  for (int kc = 0; kc < 4; ++kc){
    bf16x8 af = *(const bf16x8*)(KB + (li << 8) + ((((kc << 6) + (g << 4))) ^ swz));
    bf16x8 wf = *(const bf16x8*)(Wp + (((24 + kc) << 6) + lane) * 8);
    y = __builtin_amdgcn_mfma_f32_16x16x32_bf16(af, wf, y, 0, 0, 0);
  }
  float bv = blo[li];
  unsigned short* yr = yb + (size_t)n * 256 + li;
  #pragma unroll
  for (int r = 0; r < 4; ++r)
    yr[((g << 2) + r) << 4] = f2bf(y[r] + bv);
}

// ---------------------------------------------------------------------------
extern "C" void kernel_launch(void* const* d_in, const int* in_sizes, int n_in,
                              void* d_out, int out_size, void* d_ws, size_t ws_size,
                              hipStream_t stream)
{
  const float* x     = (const float*)d_in[0];
  const float* Wq    = (const float*)d_in[1];
  const float* bq    = (const float*)d_in[2];
  const float* Wk    = (const float*)d_in[3];
  const float* bk    = (const float*)d_in[4];
  const float* Wv    = (const float*)d_in[5];
  const float* bv    = (const float*)d_in[6];
  const float* Wlin1 = (const float*)d_in[7];
  const float* blin1 = (const float*)d_in[8];
  const float* Wqc   = (const float*)d_in[9];
  const float* bqc   = (const float*)d_in[10];
  const float* Wkc   = (const float*)d_in[11];
  const float* bkc   = (const float*)d_in[12];
  const float* Wvl   = (const float*)d_in[13];
  const float* bvl   = (const float*)d_in[14];
  const float* Wlo   = (const float*)d_in[15];
  const float* blo   = (const float*)d_in[16];
  const float* Wlout = (const float*)d_in[17];
  const float* blout = (const float*)d_in[18];
  float* out = (float*)d_out;

  // workspace (lifetimes):
  // 0          Qw bf16 33.5M (dead after attn) | yb bf16 8.4M (patch2 ->)
  // 33554432   Kw bf16 33.5M (dead after attn)
  // 67108864   xb bf16 8.4M (prep -> lin1 residual)   [NO aliasing]
  // 100663296  Ow bf16 33.5M (attn -> lin1 A)
  // 134217728  Vtw bf16 33.5M (dead after attn; tail aliased by x1b below ok)
  // 150994944  x1b bf16 8.4M (lin1 -> patch2, Wlout residual)
  // 167772160  Wqkvb 1.57M | 169345024 Wlin1b 0.52M | 169869312 Wloutb 0.13M
  // 170000384  Wp 28.7K
  char* w = (char*)d_ws;
  unsigned short* Qw  = (unsigned short*)w;
  unsigned short* yb  = (unsigned short*)w;
  unsigned short* Kw  = (unsigned short*)(w + 33554432);
  unsigned short* xb  = (unsigned short*)(w + 67108864);
  unsigned short* Ow  = (unsigned short*)(w + 100663296);
  unsigned short* Vtw = (unsigned short*)(w + 134217728);
  unsigned short* x1b = (unsigned short*)(w + 150994944);
  unsigned short* Wqkvb  = (unsigned short*)(w + 167772160);
  unsigned short* Wlin1b = (unsigned short*)(w + 169345024);
  unsigned short* Wloutb = (unsigned short*)(w + 169869312);
  unsigned short* Wp     = (unsigned short*)(w + 170000384);

  hipFuncSetAttribute((const void*)k_attn, hipFuncAttributeMaxDynamicSharedMemorySize, 65536);
  hipFuncSetAttribute((const void*)k_gemm<0>, hipFuncAttributeMaxDynamicSharedMemorySize, 65536);
  hipFuncSetAttribute((const void*)k_gemm_ln<0>, hipFuncAttributeMaxDynamicSharedMemorySize, 40960);
  hipFuncSetAttribute((const void*)k_gemm_ln<1>, hipFuncAttributeMaxDynamicSharedMemorySize, 40960);
  hipFuncSetAttribute((const void*)k_patch2, hipFuncAttributeMaxDynamicSharedMemorySize, 65536);

  // ---- prep (single launch) ----
  k_prep_all<<<5191, 256, 0, stream>>>(x, Wq, Wk, Wv, Wlin1, Wlout,
                                       Wqc, Wkc, Wvl, Wlo,
                                       xb, Wqkvb, Wlin1b, Wloutb, Wp);

  // ---- QKV projection (V written to tiled VtT) ----
  k_gemm<0><<<dim3(128, 24), 256, 65536, stream>>>(xb, Wqkvb, bq, bk, bv,
                                                   Qw, Kw, Vtw, 256);
  k_attn<<<dim3(2, 128), 512, 65536, stream>>>(Qw, Kw, Vtw, Ow);

  // ---- lin1 + fused LN -> bf16 x1b (resid = bf16 xb) ----
  k_gemm_ln<1><<<256, 256, 40960, stream>>>(Ow, Wlin1b, blin1, xb, x1b, 1024);

  // ---- patch attention (bf16 input) ----
  k_patch2<<<4096, 256, 65536, stream>>>(x1b, Wp, bqc, bkc, bvl, blo, yb);

  // ---- Wlout + fused LN -> f32 out (resid = bf16 x1b) ----
  k_gemm_ln<0><<<256, 256, 40960, stream>>>(yb, Wloutb, blout, x1b, out, 256);
}